// Round 2
// baseline (3202.235 us; speedup 1.0000x reference)
//
#include <hip/hip_runtime.h>
#include <hip/hip_bf16.h>
#include <math.h>

#define DI __device__ __forceinline__

namespace {

constexpr int L = 4096;
constexpr float EPS = 1e-5f;
constexpr float SCALEF = 0.08838834764831845f;  // 128^-0.5

typedef unsigned short u16;
typedef unsigned int u32;

DI float b2f(u16 h){ u32 u = ((u32)h) << 16; float f; __builtin_memcpy(&f, &u, 4); return f; }
DI u16 f2b(float f){ u32 u; __builtin_memcpy(&u, &f, 4); u32 r = u + 0x7fffu + ((u >> 16) & 1u); return (u16)(r >> 16); }
DI float sigmoidf(float x){ return 1.f / (1.f + __expf(-x)); }

// ---------------------------------------------------------------- LN (shared by LN1/LN2)
__global__ __launch_bounds__(256) void ln_kernel(
    const float* __restrict__ x, const float* __restrict__ g,
    const float* __restrict__ bt, float* __restrict__ o)
{
  const int tid = threadIdx.x;
  const int pos = blockIdx.x * 64 + (tid >> 2);
  const int part = tid & 3;
  const int b = pos >> 12, l = pos & (L - 1);
  const float* xb = x + (size_t)b * 128 * L + l;
  float s = 0.f, ss = 0.f;
  #pragma unroll
  for (int i = 0; i < 32; i++){
    float v = xb[(size_t)(part * 32 + i) * L];
    s += v; ss += v * v;
  }
  s += __shfl_xor(s, 1);  s += __shfl_xor(s, 2);
  ss += __shfl_xor(ss, 1); ss += __shfl_xor(ss, 2);
  const float m = s * (1.f / 128.f);
  const float rs = rsqrtf(ss * (1.f / 128.f) - m * m + EPS);
  float* ob = o + (size_t)b * 128 * L + l;
  #pragma unroll
  for (int i = 0; i < 32; i++){
    int d = part * 32 + i;
    float v = xb[(size_t)d * L];
    ob[(size_t)d * L] = (v - m) * rs * g[d] + bt[d];
  }
}

// ---------------------------------------------------------------- shared f32 GEMM tile, K=64 chunk
// acc[j][i] += sum_dd w_s[j*16+og][dd] * a_s[i*16+lg][dd]
DI void gemm_tile64(const float (*a_s)[68], const float (*w_s)[68],
                    int og, int lg, float acc[4][4])
{
  #pragma unroll
  for (int dc = 0; dc < 8; dc++){
    float4 a[4][2], wv[4][2];
    #pragma unroll
    for (int i = 0; i < 4; i++){
      a[i][0] = *(const float4*)&a_s[i * 16 + lg][dc * 8];
      a[i][1] = *(const float4*)&a_s[i * 16 + lg][dc * 8 + 4];
    }
    #pragma unroll
    for (int j = 0; j < 4; j++){
      wv[j][0] = *(const float4*)&w_s[j * 16 + og][dc * 8];
      wv[j][1] = *(const float4*)&w_s[j * 16 + og][dc * 8 + 4];
    }
    #pragma unroll
    for (int j = 0; j < 4; j++)
      #pragma unroll
      for (int i = 0; i < 4; i++)
        acc[j][i] += wv[j][0].x * a[i][0].x + wv[j][0].y * a[i][0].y
                   + wv[j][0].z * a[i][0].z + wv[j][0].w * a[i][0].w
                   + wv[j][1].x * a[i][1].x + wv[j][1].y * a[i][1].y
                   + wv[j][1].z * a[i][1].z + wv[j][1].w * a[i][1].w;
  }
}

// ---------------------------------------------------------------- qkv: dwconv(K=3)+BN+pointwise
// grid (16 o-blocks, 64 l-blocks, 8 b). out: bf16 [n=b*8+h][l][dd] (split layout).
__global__ __launch_bounds__(256, 2) void qkv_kernel(
    const float* __restrict__ xn, const float* __restrict__ dw,
    const float* __restrict__ bng, const float* __restrict__ bnb,
    const float* __restrict__ bnm, const float* __restrict__ bnv,
    const float* __restrict__ pw, u16* __restrict__ outp)
{
  __shared__ float smem[2 * 64 * 68];      // 34.8 KB
  float (*y_s)[68] = (float(*)[68])smem;
  float (*w_s)[68] = (float(*)[68])(smem + 64 * 68);
  const int tid = threadIdx.x;
  const int ob = blockIdx.x;   // 0..15
  const int lb = blockIdx.y;   // 0..63
  const int b  = blockIdx.z;
  const int l0 = lb * 64, o0 = ob * 64;
  const int og = tid >> 4, lg = tid & 15;
  float acc[4][4] = {};

  for (int kc = 0; kc < 2; kc++){
    __syncthreads();
    #pragma unroll
    for (int i = 0; i < 16; i++){          // y tile: 64 l x 64 d
      int idx = tid + 256 * i;
      int l = idx & 63, dd = idx >> 6;
      int d = kc * 64 + dd;
      int gl = l0 + l;
      const float* xr = xn + ((size_t)b * 128 + d) * L + gl;
      float xm = (gl > 0)     ? xr[-1] : 0.f;
      float xc = xr[0];
      float xp = (gl < L - 1) ? xr[1]  : 0.f;
      float conv = dw[d * 3 + 0] * xm + dw[d * 3 + 1] * xc + dw[d * 3 + 2] * xp;
      float sD = bng[d] * rsqrtf(bnv[d] + EPS);
      y_s[l][dd] = (conv - bnm[d]) * sD + bnb[d];
    }
    #pragma unroll
    for (int i = 0; i < 4; i++){           // w tile: 64 o x 64 d (float4)
      int idx = tid + 256 * i;
      int o = idx >> 4, c4 = idx & 15;
      *(float4*)&w_s[o][c4 * 4] =
          *(const float4*)&pw[(size_t)(o0 + o) * 128 + kc * 64 + c4 * 4];
    }
    __syncthreads();
    gemm_tile64(y_s, w_s, og, lg, acc);
  }

  // transpose through LDS for coalesced position-major bf16 writes
  __syncthreads();
  float (*st)[68] = (float(*)[68])smem;
  #pragma unroll
  for (int j = 0; j < 4; j++)
    #pragma unroll
    for (int i = 0; i < 4; i++)
      st[i * 16 + lg][j * 16 + og] = acc[j][i];
  __syncthreads();
  const int n = (b << 3) + (o0 >> 7);
  const int dd0 = o0 & 127;
  #pragma unroll
  for (int i = 0; i < 2; i++){             // 64x64 outputs as uint4 (8 bf16)
    int idx = tid + 256 * i;
    int l = idx >> 3, c8 = idx & 7;
    u16 pack[8];
    #pragma unroll
    for (int m = 0; m < 8; m++) pack[m] = f2b(st[l][c8 * 8 + m]);
    uint4 uu; __builtin_memcpy(&uu, pack, 16);
    *(uint4*)&outp[((size_t)n * L + l0 + l) * 128 + dd0 + c8 * 8] = uu;
  }
}

// ---------------------------------------------------------------- softmax over d (rows of 128), in-place bf16
__global__ __launch_bounds__(256) void softmax_kernel(u16* __restrict__ kt)
{
  const int row = blockIdx.x * 4 + (threadIdx.x >> 6);
  const int lane = threadIdx.x & 63;
  u16* r = kt + (size_t)row * 128;
  float v0 = b2f(r[lane]), v1 = b2f(r[lane + 64]);
  float mx = fmaxf(v0, v1);
  #pragma unroll
  for (int o = 32; o; o >>= 1) mx = fmaxf(mx, __shfl_xor(mx, o));
  float e0 = __expf(v0 - mx), e1 = __expf(v1 - mx);
  float s = e0 + e1;
  #pragma unroll
  for (int o = 32; o; o >>= 1) s += __shfl_xor(s, o);
  float inv = 1.f / s;
  r[lane] = f2b(e0 * inv);
  r[lane + 64] = f2b(e1 * inv);
}

// ---------------------------------------------------------------- w2T / c2 precompute (gate pw folded with dw*BN)
__global__ void prep_kernel(const float* __restrict__ dwc_dw, const float* __restrict__ g,
                            const float* __restrict__ bb, const float* __restrict__ m,
                            const float* __restrict__ v, const float* __restrict__ pw,
                            float* __restrict__ w2T, float* __restrict__ c2)
{
  int e = threadIdx.x;  // 128 threads
  if (e < 128){
    float cacc = 0.f;
    for (int d = 0; d < 128; d++){
      float s = g[d] * rsqrtf(v[d] + EPS);
      float wv = pw[e * 128 + d];
      w2T[d * 128 + e] = wv * dwc_dw[d] * s;
      cacc += wv * (bb[d] - m[d] * s);
    }
    c2[e] = cacc;
  }
}

// ---------------------------------------------------------------- kk partials: kk[n][d][e] = sum_x q[x][d]*ks[x][e]
// grid (4 L-splits, 64 n). Each block covers 1024 positions; partials to kkp.
__global__ __launch_bounds__(256, 2) void kk_kernel(
    const u16* __restrict__ qt, const u16* __restrict__ kt,
    float* __restrict__ kkp)
{
  __shared__ float q_s[32][132];
  __shared__ float k_s[32][132];
  const int tid = threadIdx.x;
  const int sp = blockIdx.x;   // 0..3
  const int n  = blockIdx.y;
  const int x0 = sp * 1024;
  const int dg = tid >> 4, eg = tid & 15;
  float acc[8][8] = {};
  for (int c = 0; c < 32; c++){
    __syncthreads();
    #pragma unroll
    for (int i = 0; i < 16; i++){
      int idx = tid + 256 * i;           // 32*128
      int xx = idx >> 7, d = idx & 127;
      size_t gidx = ((size_t)n * L + x0 + c * 32 + xx) * 128 + d;
      q_s[xx][d] = b2f(qt[gidx]);
      k_s[xx][d] = b2f(kt[gidx]);
    }
    __syncthreads();
    #pragma unroll 4
    for (int xx = 0; xx < 32; xx++){
      float4 q0 = *(const float4*)&q_s[xx][dg * 8];
      float4 q1 = *(const float4*)&q_s[xx][dg * 8 + 4];
      float4 k0 = *(const float4*)&k_s[xx][eg * 8];
      float4 k1 = *(const float4*)&k_s[xx][eg * 8 + 4];
      float qf[8] = {q0.x,q0.y,q0.z,q0.w,q1.x,q1.y,q1.z,q1.w};
      float kf[8] = {k0.x,k0.y,k0.z,k0.w,k1.x,k1.y,k1.z,k1.w};
      #pragma unroll
      for (int a = 0; a < 8; a++)
        #pragma unroll
        for (int e = 0; e < 8; e++)
          acc[a][e] += qf[a] * kf[e];
    }
  }
  float* op = kkp + (((size_t)sp * 64 + n) << 14);
  #pragma unroll
  for (int a = 0; a < 8; a++){
    *(float4*)&op[(dg * 8 + a) * 128 + eg * 8]     = make_float4(acc[a][0], acc[a][1], acc[a][2], acc[a][3]);
    *(float4*)&op[(dg * 8 + a) * 128 + eg * 8 + 4] = make_float4(acc[a][4], acc[a][5], acc[a][6], acc[a][7]);
  }
}

__global__ __launch_bounds__(256) void kkred_kernel(
    const float* __restrict__ kkp, float* __restrict__ kkb)
{
  int idx = blockIdx.x * 256 + threadIdx.x;   // 64*16384 total
  float s = 0.f;
  #pragma unroll
  for (int sp = 0; sp < 4; sp++) s += kkp[(size_t)sp * (64 * 16384) + idx];
  kkb[idx] = s * SCALEF;
}

// ---------------------------------------------------------------- fused gate + v@kk -> outt
// out[n][x][e] = sum_d v[x][d]*kk[d][e] + sigmoid(sum_d q[x][d]*w2T[d][e] + c2[e]) * v[x][e]
// grid (128 l-blocks of 32, 64 n). kk/w2T streamed from L1/L2; q,v tiles in LDS.
__global__ __launch_bounds__(256, 2) void gateout_kernel(
    const u16* __restrict__ qt, const u16* __restrict__ vt,
    const float* __restrict__ kkb, const float* __restrict__ w2T,
    const float* __restrict__ c2, u16* __restrict__ outt)
{
  __shared__ float q_s[32][132];
  __shared__ float v_s[32][132];
  const int tid = threadIdx.x;
  const int lb = blockIdx.x;   // 0..127
  const int n  = blockIdx.y;
  const int l0 = lb * 32;
  const size_t base = ((size_t)n * L + l0) * 128;
  #pragma unroll
  for (int i = 0; i < 16; i++){
    int idx = tid + 256 * i;               // 32*128
    int xx = idx >> 7, d = idx & 127;
    q_s[xx][d] = b2f(qt[base + idx]);
    v_s[xx][d] = b2f(vt[base + idx]);
  }
  __syncthreads();
  const int xg = tid >> 4, eg = tid & 15;
  const float* kkn = kkb + ((size_t)n << 14);
  float acc_o[2][8] = {}, acc_g[2][8] = {};
  #pragma unroll 2
  for (int d = 0; d < 128; d++){
    float4 k0 = *(const float4*)&kkn[d * 128 + eg * 8];
    float4 k1 = *(const float4*)&kkn[d * 128 + eg * 8 + 4];
    float4 w0 = *(const float4*)&w2T[d * 128 + eg * 8];
    float4 w1 = *(const float4*)&w2T[d * 128 + eg * 8 + 4];
    float kf[8] = {k0.x,k0.y,k0.z,k0.w,k1.x,k1.y,k1.z,k1.w};
    float wf[8] = {w0.x,w0.y,w0.z,w0.w,w1.x,w1.y,w1.z,w1.w};
    #pragma unroll
    for (int i = 0; i < 2; i++){
      float qv = q_s[i * 16 + xg][d];
      float vv = v_s[i * 16 + xg][d];
      #pragma unroll
      for (int j = 0; j < 8; j++){
        acc_o[i][j] += vv * kf[j];
        acc_g[i][j] += qv * wf[j];
      }
    }
  }
  #pragma unroll
  for (int i = 0; i < 2; i++){
    const int x = i * 16 + xg;
    u16 pack[8];
    #pragma unroll
    for (int j = 0; j < 8; j++){
      int e = eg * 8 + j;
      float gate = sigmoidf(acc_g[i][j] + c2[e]);
      pack[j] = f2b(acc_o[i][j] + gate * v_s[x][e]);
    }
    uint4 uu; __builtin_memcpy(&uu, pack, 16);
    *(uint4*)&outt[base + (size_t)x * 128 + eg * 8] = uu;
  }
}

// ---------------------------------------------------------------- out_w @ out + bias + residual -> x2 (channel-major)
__global__ __launch_bounds__(256, 2) void outw_kernel(
    const u16* __restrict__ outt, const float* __restrict__ out_w,
    const float* __restrict__ out_b, const float* __restrict__ x,
    float* __restrict__ x2)
{
  __shared__ float smem[2 * 64 * 68];
  float (*in_s)[68] = (float(*)[68])smem;
  float (*w_s)[68]  = (float(*)[68])(smem + 64 * 68);
  const int tid = threadIdx.x;
  const int lb = blockIdx.x;   // 64
  const int obk = blockIdx.y;  // 2
  const int b = blockIdx.z;
  const int l0 = lb * 64, o0 = obk * 64;
  const int og = tid >> 4, lg = tid & 15;
  float acc[4][4] = {};
  for (int t = 0; t < 16; t++){
    int h = t >> 1, half = t & 1;
    __syncthreads();
    #pragma unroll
    for (int i = 0; i < 2; i++){           // in: 64 x 64 bf16 via uint4
      int idx = tid + 256 * i;
      int xx = idx >> 3, c8 = idx & 7;
      uint4 u = *(const uint4*)&outt[((size_t)(b * 8 + h) * L + l0 + xx) * 128 + half * 64 + c8 * 8];
      u16 us[8]; __builtin_memcpy(us, &u, 16);
      #pragma unroll
      for (int m = 0; m < 8; m++) in_s[xx][c8 * 8 + m] = b2f(us[m]);
    }
    #pragma unroll
    for (int i = 0; i < 4; i++){           // w: 64 x 64 f32 via float4
      int idx = tid + 256 * i;
      int o = idx >> 4, c4 = idx & 15;
      *(float4*)&w_s[o][c4 * 4] =
          *(const float4*)&out_w[(size_t)(o0 + o) * 1024 + h * 128 + half * 64 + c4 * 4];
    }
    __syncthreads();
    gemm_tile64(in_s, w_s, og, lg, acc);
  }
  #pragma unroll
  for (int j = 0; j < 4; j++){
    int o = o0 + j * 16 + og;
    float bias = out_b[o];
    #pragma unroll
    for (int i = 0; i < 4; i++){
      int gl = l0 + i * 16 + lg;
      size_t idx = ((size_t)b * 128 + o) * L + gl;
      x2[idx] = acc[j][i] + bias + x[idx];
    }
  }
}

// ---------------------------------------------------------------- ff1 + exact gelu -> hb (bf16 channel-major)
__global__ __launch_bounds__(256, 2) void ff1_kernel(
    const float* __restrict__ xn2, const float* __restrict__ w1,
    const float* __restrict__ b1, u16* __restrict__ hb)
{
  __shared__ float smem[2 * 64 * 68];
  float (*in_s)[68] = (float(*)[68])smem;
  float (*w_s)[68]  = (float(*)[68])(smem + 64 * 68);
  const int tid = threadIdx.x;
  const int lb = blockIdx.x;  // 64
  const int fb = blockIdx.y;  // 8
  const int b  = blockIdx.z;
  const int l0 = lb * 64, f0 = fb * 64;
  const int og = tid >> 4, lg = tid & 15;
  float acc[4][4] = {};
  for (int kc = 0; kc < 2; kc++){
    __syncthreads();
    #pragma unroll
    for (int i = 0; i < 16; i++){
      int idx = tid + 256 * i;             // 64 d x 64 x
      int dd = idx >> 6, xx = idx & 63;
      in_s[xx][dd] = xn2[((size_t)b * 128 + kc * 64 + dd) * L + l0 + xx];
    }
    #pragma unroll
    for (int i = 0; i < 4; i++){
      int idx = tid + 256 * i;
      int o = idx >> 4, c4 = idx & 15;
      *(float4*)&w_s[o][c4 * 4] =
          *(const float4*)&w1[(size_t)(f0 + o) * 128 + kc * 64 + c4 * 4];
    }
    __syncthreads();
    gemm_tile64(in_s, w_s, og, lg, acc);
  }
  #pragma unroll
  for (int j = 0; j < 4; j++){
    int f = f0 + j * 16 + og;
    float bias = b1[f];
    #pragma unroll
    for (int i = 0; i < 4; i++){
      float v = acc[j][i] + bias;
      float ge = 0.5f * v * (1.f + erff(v * 0.70710678118654752f));
      hb[((size_t)b * 512 + f) * L + l0 + i * 16 + lg] = f2b(ge);
    }
  }
}

// ---------------------------------------------------------------- ff2 + bias + residual -> d_out
__global__ __launch_bounds__(256, 2) void ff2_kernel(
    const u16* __restrict__ hb, const float* __restrict__ w2,
    const float* __restrict__ b2, const float* __restrict__ x2,
    float* __restrict__ outp)
{
  __shared__ float smem[2 * 64 * 68];
  float (*in_s)[68] = (float(*)[68])smem;
  float (*w_s)[68]  = (float(*)[68])(smem + 64 * 68);
  const int tid = threadIdx.x;
  const int lb = blockIdx.x;   // 64
  const int obk = blockIdx.y;  // 2
  const int b = blockIdx.z;
  const int l0 = lb * 64, o0 = obk * 64;
  const int og = tid >> 4, lg = tid & 15;
  float acc[4][4] = {};
  for (int kc = 0; kc < 8; kc++){
    __syncthreads();
    #pragma unroll
    for (int i = 0; i < 16; i++){
      int idx = tid + 256 * i;
      int dd = idx >> 6, xx = idx & 63;
      in_s[xx][dd] = b2f(hb[((size_t)b * 512 + kc * 64 + dd) * L + l0 + xx]);
    }
    #pragma unroll
    for (int i = 0; i < 4; i++){
      int idx = tid + 256 * i;
      int o = idx >> 4, c4 = idx & 15;
      *(float4*)&w_s[o][c4 * 4] =
          *(const float4*)&w2[(size_t)(o0 + o) * 512 + kc * 64 + c4 * 4];
    }
    __syncthreads();
    gemm_tile64(in_s, w_s, og, lg, acc);
  }
  #pragma unroll
  for (int j = 0; j < 4; j++){
    int o = o0 + j * 16 + og;
    float bias = b2[o];
    #pragma unroll
    for (int i = 0; i < 4; i++){
      int gl = l0 + i * 16 + lg;
      size_t idx = ((size_t)b * 128 + o) * L + gl;
      outp[idx] = acc[j][i] + bias + x2[idx];
    }
  }
}

} // namespace

extern "C" void kernel_launch(void* const* d_in, const int* in_sizes, int n_in,
                              void* d_out, int out_size, void* d_ws, size_t ws_size,
                              hipStream_t stream)
{
  const float* x      = (const float*)d_in[0];
  const float* ln1_g  = (const float*)d_in[1];
  const float* ln1_b  = (const float*)d_in[2];
  const float* q_dw   = (const float*)d_in[3];
  const float* q_bng  = (const float*)d_in[4];
  const float* q_bnb  = (const float*)d_in[5];
  const float* q_bnm  = (const float*)d_in[6];
  const float* q_bnv  = (const float*)d_in[7];
  const float* q_pw   = (const float*)d_in[8];
  const float* k_dw   = (const float*)d_in[9];
  const float* k_bng  = (const float*)d_in[10];
  const float* k_bnb  = (const float*)d_in[11];
  const float* k_bnm  = (const float*)d_in[12];
  const float* k_bnv  = (const float*)d_in[13];
  const float* k_pw   = (const float*)d_in[14];
  const float* v_dw   = (const float*)d_in[15];
  const float* v_bng  = (const float*)d_in[16];
  const float* v_bnb  = (const float*)d_in[17];
  const float* v_bnm  = (const float*)d_in[18];
  const float* v_bnv  = (const float*)d_in[19];
  const float* v_pw   = (const float*)d_in[20];
  const float* dwc_dw  = (const float*)d_in[21];
  const float* dwc_bng = (const float*)d_in[22];
  const float* dwc_bnb = (const float*)d_in[23];
  const float* dwc_bnm = (const float*)d_in[24];
  const float* dwc_bnv = (const float*)d_in[25];
  const float* dwc_pw  = (const float*)d_in[26];
  const float* out_w  = (const float*)d_in[27];
  const float* out_b  = (const float*)d_in[28];
  const float* ln2_g  = (const float*)d_in[29];
  const float* ln2_b  = (const float*)d_in[30];
  const float* ff_w1  = (const float*)d_in[31];
  const float* ff_b1  = (const float*)d_in[32];
  const float* ff_w2  = (const float*)d_in[33];
  const float* ff_b2  = (const float*)d_in[34];
  float* out = (float*)d_out;

  // ---- workspace layout with lifetime-based aliasing (total 224 MB + 68 KB) ----
  // [0,64)    qt              (live: qkv .. gateout)
  // [64,128)  kt (qkv..kk) -> outt (gateout..outw) -> hb (ff1..ff2)
  // [128,192) vt              (live: qkv .. gateout)
  // [192,208) xn f32 (ln1..qkv) -> kkb 4MB (kkred..gateout) -> xn2 (ln2..ff1)
  // [208,224) kkp 16MB (kk..kkred) -> x2 (outw..ff2)
  // [224, +68KB) w2T + c2     (prep .. gateout)
  char* w = (char*)d_ws;
  u16*  qt   = (u16*)(w);
  u16*  kt   = (u16*)(w + (64ull  << 20));
  u16*  outt = kt;
  u16*  hb   = kt;
  u16*  vt   = (u16*)(w + (128ull << 20));
  float* xn  = (float*)(w + (192ull << 20));
  float* kkb = xn;
  float* xn2 = xn;
  float* kkp = (float*)(w + (208ull << 20));
  float* x2  = kkp;
  float* w2T = (float*)(w + (224ull << 20));
  float* c2  = (float*)(w + (224ull << 20) + 65536);

  ln_kernel<<<512, 256, 0, stream>>>(x, ln1_g, ln1_b, xn);
  prep_kernel<<<1, 128, 0, stream>>>(dwc_dw, dwc_bng, dwc_bnb, dwc_bnm, dwc_bnv, dwc_pw, w2T, c2);

  dim3 gqkv(16, 64, 8);
  qkv_kernel<<<gqkv, 256, 0, stream>>>(xn, q_dw, q_bng, q_bnb, q_bnm, q_bnv, q_pw, qt);
  qkv_kernel<<<gqkv, 256, 0, stream>>>(xn, k_dw, k_bng, k_bnb, k_bnm, k_bnv, k_pw, kt);
  qkv_kernel<<<gqkv, 256, 0, stream>>>(xn, v_dw, v_bng, v_bnb, v_bnm, v_bnv, v_pw, vt);

  softmax_kernel<<<65536, 256, 0, stream>>>(kt);
  kk_kernel<<<dim3(4, 64), 256, 0, stream>>>(qt, kt, kkp);
  kkred_kernel<<<4096, 256, 0, stream>>>(kkp, kkb);
  gateout_kernel<<<dim3(128, 64), 256, 0, stream>>>(qt, vt, kkb, w2T, c2, outt);
  outw_kernel<<<dim3(64, 2, 8), 256, 0, stream>>>(outt, out_w, out_b, x, x2);

  ln_kernel<<<512, 256, 0, stream>>>(x2, ln2_g, ln2_b, xn2);
  ff1_kernel<<<dim3(64, 8, 8), 256, 0, stream>>>(xn2, ff_w1, ff_b1, hb);
  ff2_kernel<<<dim3(64, 2, 8), 256, 0, stream>>>(hb, ff_w2, ff_b2, x2, out);
}

// Round 3
// 1685.475 us; speedup vs baseline: 1.8999x; 1.8999x over previous
//
#include <hip/hip_runtime.h>
#include <hip/hip_bf16.h>
#include <math.h>

#define DI __device__ __forceinline__

namespace {

constexpr int L = 4096;
constexpr float EPS = 1e-5f;
constexpr float SCALEF = 0.08838834764831845f;  // 128^-0.5

typedef unsigned short u16;
typedef unsigned int u32;
typedef __attribute__((ext_vector_type(8))) short bf16x8;
typedef __attribute__((ext_vector_type(4))) float f32x4;

DI float b2f(u16 h){ u32 u = ((u32)h) << 16; float f; __builtin_memcpy(&f, &u, 4); return f; }
DI u16 f2b(float f){ u32 u; __builtin_memcpy(&u, &f, 4); u32 r = u + 0x7fffu + ((u >> 16) & 1u); return (u16)(r >> 16); }
DI float sigmoidf(float x){ return 1.f / (1.f + __expf(-x)); }

// ---------------------------------------------------------------- LN (shared by LN1/LN2)
__global__ __launch_bounds__(256) void ln_kernel(
    const float* __restrict__ x, const float* __restrict__ g,
    const float* __restrict__ bt, float* __restrict__ o)
{
  const int tid = threadIdx.x;
  const int pos = blockIdx.x * 64 + (tid >> 2);
  const int part = tid & 3;
  const int b = pos >> 12, l = pos & (L - 1);
  const float* xb = x + (size_t)b * 128 * L + l;
  float s = 0.f, ss = 0.f;
  #pragma unroll
  for (int i = 0; i < 32; i++){
    float v = xb[(size_t)(part * 32 + i) * L];
    s += v; ss += v * v;
  }
  s += __shfl_xor(s, 1);  s += __shfl_xor(s, 2);
  ss += __shfl_xor(ss, 1); ss += __shfl_xor(ss, 2);
  const float m = s * (1.f / 128.f);
  const float rs = rsqrtf(ss * (1.f / 128.f) - m * m + EPS);
  float* ob = o + (size_t)b * 128 * L + l;
  #pragma unroll
  for (int i = 0; i < 32; i++){
    int d = part * 32 + i;
    float v = xb[(size_t)d * L];
    ob[(size_t)d * L] = (v - m) * rs * g[d] + bt[d];
  }
}

// ---------------------------------------------------------------- pack pw (q,k,v) to bf16 B-frag layout
// wpk[ph=p*8+h][off]: off = (o>>4)*2048 + d8*128 + ((o&15)^d8)*8 + j, d8 = d>>3
__global__ __launch_bounds__(256) void wpack_kernel(
    const float* __restrict__ q_pw, const float* __restrict__ k_pw,
    const float* __restrict__ v_pw, u16* __restrict__ wpk)
{
  int item = blockIdx.x * 256 + threadIdx.x;   // 49152 items
  int d8 = item & 15;
  int o  = (item >> 4) & 127;
  int ph = item >> 11;                          // 0..23
  int p = ph >> 3, h = ph & 7;
  const float* pw = (p == 0) ? q_pw : (p == 1 ? k_pw : v_pw);
  const float* src = pw + (size_t)(h * 128 + o) * 128 + d8 * 8;
  u16 pk[8];
  #pragma unroll
  for (int j = 0; j < 8; j++) pk[j] = f2b(src[j]);
  uint4 uu; __builtin_memcpy(&uu, pk, 16);
  *(uint4*)&wpk[((size_t)ph << 14) + ((o >> 4) << 11) + (d8 << 7) + (((o & 15) ^ d8) << 3)] = uu;
}

// ---------------------------------------------------------------- fused qkv: dwconv+BN (f32) -> MFMA pointwise -> bf16 split layout
struct QkvArgs {
  const float* dw[3];
  const float* bng[3];
  const float* bnb[3];
  const float* bnm[3];
  const float* bnv[3];
  u16* outp[3];
};

__global__ __launch_bounds__(256, 3) void qkv_fused_kernel(
    const float* __restrict__ xn, const u16* __restrict__ wpk, QkvArgs args)
{
  __shared__ u16 y_s[64 * 128];      // 16 KB, A-frag layout
  __shared__ u16 w_s[128 * 128];     // 32 KB, B-frag layout; aliased as out-stage [64][136]
  const int tid = threadIdx.x;
  const int lb = blockIdx.x;   // 0..63
  const int oh = blockIdx.y;   // 0..1
  const int b  = blockIdx.z;   // 0..7
  const int l0 = lb * 64;
  const int lane = tid & 63, wv = tid >> 6;
  const int nn = lane & 15, quad = lane >> 4;

  for (int p = 0; p < 3; p++){
    const float* dw  = args.dw[p];
    const float* bng = args.bng[p];
    const float* bnb = args.bnb[p];
    const float* bnm = args.bnm[p];
    const float* bnv = args.bnv[p];
    u16* outp = args.outp[p];

    // ---- stage y_p = BN(dwconv(xn)) into A-frag LDS layout ----
    __syncthreads();
    #pragma unroll
    for (int it = 0; it < 4; it++){
      int item = tid + 256 * it;          // 1024 = 64 l x 16 d8
      int l = item & 63, d8 = item >> 6;
      int gl = l0 + l;
      u16 pk[8];
      #pragma unroll
      for (int jj = 0; jj < 8; jj++){
        int d = d8 * 8 + jj;
        const float* xr = xn + ((size_t)b * 128 + d) * L + gl;
        float xm = (gl > 0)     ? xr[-1] : 0.f;
        float xc = xr[0];
        float xp = (gl < L - 1) ? xr[1]  : 0.f;
        float conv = dw[d * 3 + 0] * xm + dw[d * 3 + 1] * xc + dw[d * 3 + 2] * xp;
        float sD = bng[d] * rsqrtf(bnv[d] + EPS);
        pk[jj] = f2b((conv - bnm[d]) * sD + bnb[d]);
      }
      uint4 uu; __builtin_memcpy(&uu, pk, 16);
      *(uint4*)&y_s[((l >> 4) << 11) + (d8 << 7) + ((l & 15) << 3)] = uu;
    }
    __syncthreads();

    // ---- load A-frags for this wave's 16 l rows ----
    bf16x8 af[4];
    #pragma unroll
    for (int dc = 0; dc < 4; dc++)
      af[dc] = *(const bf16x8*)&y_s[(wv << 11) + (((dc << 2) + quad) << 7) + (nn << 3)];

    for (int hh = 0; hh < 4; hh++){
      const int h = oh * 4 + hh;
      const int ph = p * 8 + h;
      __syncthreads();   // protect w_s from previous chunk's out-stage readers
      // ---- stage pre-packed W chunk (pure 32 KB copy) ----
      const u16* src = wpk + ((size_t)ph << 14);
      #pragma unroll
      for (int it = 0; it < 8; it++){
        int idx = (tid + 256 * it) << 3;
        *(uint4*)&w_s[idx] = *(const uint4*)&src[idx];
      }
      __syncthreads();

      // ---- MFMA: 16 l x 128 o per wave ----
      f32x4 acc[8];
      #pragma unroll
      for (int os = 0; os < 8; os++) acc[os] = (f32x4){0.f, 0.f, 0.f, 0.f};
      #pragma unroll
      for (int os = 0; os < 8; os++){
        #pragma unroll
        for (int dc = 0; dc < 4; dc++){
          int d8 = (dc << 2) + quad;
          bf16x8 bf = *(const bf16x8*)&w_s[(os << 11) + (d8 << 7) + ((nn ^ d8) << 3)];
          acc[os] = __builtin_amdgcn_mfma_f32_16x16x32_bf16(af[dc], bf, acc[os], 0, 0, 0);
        }
      }
      __syncthreads();

      // ---- out-stage to LDS [64][136] bf16, then full 256B-row global writes ----
      u16* st = w_s;
      #pragma unroll
      for (int os = 0; os < 8; os++){
        #pragma unroll
        for (int r = 0; r < 4; r++){
          int ll = (wv << 4) + (quad << 2) + r;
          st[ll * 136 + (os << 4) + nn] = f2b(acc[os][r]);
        }
      }
      __syncthreads();
      size_t gbase = ((size_t)(b * 8 + h) * L + l0) * 128;
      #pragma unroll
      for (int it = 0; it < 4; it++){
        int row = (tid >> 4) + (it << 4);
        int c16 = tid & 15;
        uint4 uu = *(const uint4*)&st[row * 136 + (c16 << 3)];
        *(uint4*)&outp[gbase + (size_t)row * 128 + (c16 << 3)] = uu;
      }
    }
  }
}

// ---------------------------------------------------------------- softmax over d (rows of 128), in-place bf16
__global__ __launch_bounds__(256) void softmax_kernel(u16* __restrict__ kt)
{
  const int row = blockIdx.x * 4 + (threadIdx.x >> 6);
  const int lane = threadIdx.x & 63;
  u16* r = kt + (size_t)row * 128;
  float v0 = b2f(r[lane]), v1 = b2f(r[lane + 64]);
  float mx = fmaxf(v0, v1);
  #pragma unroll
  for (int o = 32; o; o >>= 1) mx = fmaxf(mx, __shfl_xor(mx, o));
  float e0 = __expf(v0 - mx), e1 = __expf(v1 - mx);
  float s = e0 + e1;
  #pragma unroll
  for (int o = 32; o; o >>= 1) s += __shfl_xor(s, o);
  float inv = 1.f / s;
  r[lane] = f2b(e0 * inv);
  r[lane + 64] = f2b(e1 * inv);
}

// ---------------------------------------------------------------- w2T / c2 precompute (gate pw folded with dw*BN)
__global__ void prep_kernel(const float* __restrict__ dwc_dw, const float* __restrict__ g,
                            const float* __restrict__ bb, const float* __restrict__ m,
                            const float* __restrict__ v, const float* __restrict__ pw,
                            float* __restrict__ w2T, float* __restrict__ c2)
{
  int e = threadIdx.x;  // 128 threads
  if (e < 128){
    float cacc = 0.f;
    for (int d = 0; d < 128; d++){
      float s = g[d] * rsqrtf(v[d] + EPS);
      float wv = pw[e * 128 + d];
      w2T[d * 128 + e] = wv * dwc_dw[d] * s;
      cacc += wv * (bb[d] - m[d] * s);
    }
    c2[e] = cacc;
  }
}

// ---------------------------------------------------------------- kk partials: kk[n][d][e] = sum_x q[x][d]*ks[x][e]
__global__ __launch_bounds__(256, 2) void kk_kernel(
    const u16* __restrict__ qt, const u16* __restrict__ kt,
    float* __restrict__ kkp)
{
  __shared__ float q_s[32][132];
  __shared__ float k_s[32][132];
  const int tid = threadIdx.x;
  const int sp = blockIdx.x;   // 0..3
  const int n  = blockIdx.y;
  const int x0 = sp * 1024;
  const int dg = tid >> 4, eg = tid & 15;
  float acc[8][8] = {};
  for (int c = 0; c < 32; c++){
    __syncthreads();
    #pragma unroll
    for (int i = 0; i < 16; i++){
      int idx = tid + 256 * i;           // 32*128
      int xx = idx >> 7, d = idx & 127;
      size_t gidx = ((size_t)n * L + x0 + c * 32 + xx) * 128 + d;
      q_s[xx][d] = b2f(qt[gidx]);
      k_s[xx][d] = b2f(kt[gidx]);
    }
    __syncthreads();
    #pragma unroll 4
    for (int xx = 0; xx < 32; xx++){
      float4 q0 = *(const float4*)&q_s[xx][dg * 8];
      float4 q1 = *(const float4*)&q_s[xx][dg * 8 + 4];
      float4 k0 = *(const float4*)&k_s[xx][eg * 8];
      float4 k1 = *(const float4*)&k_s[xx][eg * 8 + 4];
      float qf[8] = {q0.x,q0.y,q0.z,q0.w,q1.x,q1.y,q1.z,q1.w};
      float kf[8] = {k0.x,k0.y,k0.z,k0.w,k1.x,k1.y,k1.z,k1.w};
      #pragma unroll
      for (int a = 0; a < 8; a++)
        #pragma unroll
        for (int e = 0; e < 8; e++)
          acc[a][e] += qf[a] * kf[e];
    }
  }
  float* op = kkp + (((size_t)sp * 64 + n) << 14);
  #pragma unroll
  for (int a = 0; a < 8; a++){
    *(float4*)&op[(dg * 8 + a) * 128 + eg * 8]     = make_float4(acc[a][0], acc[a][1], acc[a][2], acc[a][3]);
    *(float4*)&op[(dg * 8 + a) * 128 + eg * 8 + 4] = make_float4(acc[a][4], acc[a][5], acc[a][6], acc[a][7]);
  }
}

__global__ __launch_bounds__(256) void kkred_kernel(
    const float* __restrict__ kkp, float* __restrict__ kkb)
{
  int idx = blockIdx.x * 256 + threadIdx.x;   // 64*16384 total
  float s = 0.f;
  #pragma unroll
  for (int sp = 0; sp < 4; sp++) s += kkp[(size_t)sp * (64 * 16384) + idx];
  kkb[idx] = s * SCALEF;
}

// ---------------------------------------------------------------- fused gate + v@kk -> outt
__global__ __launch_bounds__(256, 2) void gateout_kernel(
    const u16* __restrict__ qt, const u16* __restrict__ vt,
    const float* __restrict__ kkb, const float* __restrict__ w2T,
    const float* __restrict__ c2, u16* __restrict__ outt)
{
  __shared__ float q_s[32][132];
  __shared__ float v_s[32][132];
  const int tid = threadIdx.x;
  const int lb = blockIdx.x;   // 0..127
  const int n  = blockIdx.y;
  const int l0 = lb * 32;
  const size_t base = ((size_t)n * L + l0) * 128;
  #pragma unroll
  for (int i = 0; i < 16; i++){
    int idx = tid + 256 * i;               // 32*128
    int xx = idx >> 7, d = idx & 127;
    q_s[xx][d] = b2f(qt[base + idx]);
    v_s[xx][d] = b2f(vt[base + idx]);
  }
  __syncthreads();
  const int xg = tid >> 4, eg = tid & 15;
  const float* kkn = kkb + ((size_t)n << 14);
  float acc_o[2][8] = {}, acc_g[2][8] = {};
  #pragma unroll 2
  for (int d = 0; d < 128; d++){
    float4 k0 = *(const float4*)&kkn[d * 128 + eg * 8];
    float4 k1 = *(const float4*)&kkn[d * 128 + eg * 8 + 4];
    float4 w0 = *(const float4*)&w2T[d * 128 + eg * 8];
    float4 w1 = *(const float4*)&w2T[d * 128 + eg * 8 + 4];
    float kf[8] = {k0.x,k0.y,k0.z,k0.w,k1.x,k1.y,k1.z,k1.w};
    float wf[8] = {w0.x,w0.y,w0.z,w0.w,w1.x,w1.y,w1.z,w1.w};
    #pragma unroll
    for (int i = 0; i < 2; i++){
      float qv = q_s[i * 16 + xg][d];
      float vv = v_s[i * 16 + xg][d];
      #pragma unroll
      for (int j = 0; j < 8; j++){
        acc_o[i][j] += vv * kf[j];
        acc_g[i][j] += qv * wf[j];
      }
    }
  }
  #pragma unroll
  for (int i = 0; i < 2; i++){
    const int x = i * 16 + xg;
    u16 pack[8];
    #pragma unroll
    for (int j = 0; j < 8; j++){
      int e = eg * 8 + j;
      float gate = sigmoidf(acc_g[i][j] + c2[e]);
      pack[j] = f2b(acc_o[i][j] + gate * v_s[x][e]);
    }
    uint4 uu; __builtin_memcpy(&uu, pack, 16);
    *(uint4*)&outt[base + (size_t)x * 128 + eg * 8] = uu;
  }
}

// ---------------------------------------------------------------- shared f32 GEMM tile, K=64 chunk
DI void gemm_tile64(const float (*a_s)[68], const float (*w_s)[68],
                    int og, int lg, float acc[4][4])
{
  #pragma unroll
  for (int dc = 0; dc < 8; dc++){
    float4 a[4][2], wv[4][2];
    #pragma unroll
    for (int i = 0; i < 4; i++){
      a[i][0] = *(const float4*)&a_s[i * 16 + lg][dc * 8];
      a[i][1] = *(const float4*)&a_s[i * 16 + lg][dc * 8 + 4];
    }
    #pragma unroll
    for (int j = 0; j < 4; j++){
      wv[j][0] = *(const float4*)&w_s[j * 16 + og][dc * 8];
      wv[j][1] = *(const float4*)&w_s[j * 16 + og][dc * 8 + 4];
    }
    #pragma unroll
    for (int j = 0; j < 4; j++)
      #pragma unroll
      for (int i = 0; i < 4; i++)
        acc[j][i] += wv[j][0].x * a[i][0].x + wv[j][0].y * a[i][0].y
                   + wv[j][0].z * a[i][0].z + wv[j][0].w * a[i][0].w
                   + wv[j][1].x * a[i][1].x + wv[j][1].y * a[i][1].y
                   + wv[j][1].z * a[i][1].z + wv[j][1].w * a[i][1].w;
  }
}

// ---------------------------------------------------------------- out_w @ out + bias + residual -> x2 (channel-major)
__global__ __launch_bounds__(256, 2) void outw_kernel(
    const u16* __restrict__ outt, const float* __restrict__ out_w,
    const float* __restrict__ out_b, const float* __restrict__ x,
    float* __restrict__ x2)
{
  __shared__ float smem[2 * 64 * 68];
  float (*in_s)[68] = (float(*)[68])smem;
  float (*w_s)[68]  = (float(*)[68])(smem + 64 * 68);
  const int tid = threadIdx.x;
  const int lb = blockIdx.x;   // 64
  const int obk = blockIdx.y;  // 2
  const int b = blockIdx.z;
  const int l0 = lb * 64, o0 = obk * 64;
  const int og = tid >> 4, lg = tid & 15;
  float acc[4][4] = {};
  for (int t = 0; t < 16; t++){
    int h = t >> 1, half = t & 1;
    __syncthreads();
    #pragma unroll
    for (int i = 0; i < 2; i++){           // in: 64 x 64 bf16 via uint4
      int idx = tid + 256 * i;
      int xx = idx >> 3, c8 = idx & 7;
      uint4 u = *(const uint4*)&outt[((size_t)(b * 8 + h) * L + l0 + xx) * 128 + half * 64 + c8 * 8];
      u16 us[8]; __builtin_memcpy(us, &u, 16);
      #pragma unroll
      for (int m = 0; m < 8; m++) in_s[xx][c8 * 8 + m] = b2f(us[m]);
    }
    #pragma unroll
    for (int i = 0; i < 4; i++){           // w: 64 x 64 f32 via float4
      int idx = tid + 256 * i;
      int o = idx >> 4, c4 = idx & 15;
      *(float4*)&w_s[o][c4 * 4] =
          *(const float4*)&out_w[(size_t)(o0 + o) * 1024 + h * 128 + half * 64 + c4 * 4];
    }
    __syncthreads();
    gemm_tile64(in_s, w_s, og, lg, acc);
  }
  #pragma unroll
  for (int j = 0; j < 4; j++){
    int o = o0 + j * 16 + og;
    float bias = out_b[o];
    #pragma unroll
    for (int i = 0; i < 4; i++){
      int gl = l0 + i * 16 + lg;
      size_t idx = ((size_t)b * 128 + o) * L + gl;
      x2[idx] = acc[j][i] + bias + x[idx];
    }
  }
}

// ---------------------------------------------------------------- ff1 + exact gelu -> hb (bf16 channel-major)
__global__ __launch_bounds__(256, 2) void ff1_kernel(
    const float* __restrict__ xn2, const float* __restrict__ w1,
    const float* __restrict__ b1, u16* __restrict__ hb)
{
  __shared__ float smem[2 * 64 * 68];
  float (*in_s)[68] = (float(*)[68])smem;
  float (*w_s)[68]  = (float(*)[68])(smem + 64 * 68);
  const int tid = threadIdx.x;
  const int lb = blockIdx.x;  // 64
  const int fb = blockIdx.y;  // 8
  const int b  = blockIdx.z;
  const int l0 = lb * 64, f0 = fb * 64;
  const int og = tid >> 4, lg = tid & 15;
  float acc[4][4] = {};
  for (int kc = 0; kc < 2; kc++){
    __syncthreads();
    #pragma unroll
    for (int i = 0; i < 16; i++){
      int idx = tid + 256 * i;             // 64 d x 64 x
      int dd = idx >> 6, xx = idx & 63;
      in_s[xx][dd] = xn2[((size_t)b * 128 + kc * 64 + dd) * L + l0 + xx];
    }
    #pragma unroll
    for (int i = 0; i < 4; i++){
      int idx = tid + 256 * i;
      int o = idx >> 4, c4 = idx & 15;
      *(float4*)&w_s[o][c4 * 4] =
          *(const float4*)&w1[(size_t)(f0 + o) * 128 + kc * 64 + c4 * 4];
    }
    __syncthreads();
    gemm_tile64(in_s, w_s, og, lg, acc);
  }
  #pragma unroll
  for (int j = 0; j < 4; j++){
    int f = f0 + j * 16 + og;
    float bias = b1[f];
    #pragma unroll
    for (int i = 0; i < 4; i++){
      float v = acc[j][i] + bias;
      float ge = 0.5f * v * (1.f + erff(v * 0.70710678118654752f));
      hb[((size_t)b * 512 + f) * L + l0 + i * 16 + lg] = f2b(ge);
    }
  }
}

// ---------------------------------------------------------------- ff2 + bias + residual -> d_out
__global__ __launch_bounds__(256, 2) void ff2_kernel(
    const u16* __restrict__ hb, const float* __restrict__ w2,
    const float* __restrict__ b2, const float* __restrict__ x2,
    float* __restrict__ outp)
{
  __shared__ float smem[2 * 64 * 68];
  float (*in_s)[68] = (float(*)[68])smem;
  float (*w_s)[68]  = (float(*)[68])(smem + 64 * 68);
  const int tid = threadIdx.x;
  const int lb = blockIdx.x;   // 64
  const int obk = blockIdx.y;  // 2
  const int b = blockIdx.z;
  const int l0 = lb * 64, o0 = obk * 64;
  const int og = tid >> 4, lg = tid & 15;
  float acc[4][4] = {};
  for (int kc = 0; kc < 8; kc++){
    __syncthreads();
    #pragma unroll
    for (int i = 0; i < 16; i++){
      int idx = tid + 256 * i;
      int dd = idx >> 6, xx = idx & 63;
      in_s[xx][dd] = b2f(hb[((size_t)b * 512 + kc * 64 + dd) * L + l0 + xx]);
    }
    #pragma unroll
    for (int i = 0; i < 4; i++){
      int idx = tid + 256 * i;
      int o = idx >> 4, c4 = idx & 15;
      *(float4*)&w_s[o][c4 * 4] =
          *(const float4*)&w2[(size_t)(o0 + o) * 512 + kc * 64 + c4 * 4];
    }
    __syncthreads();
    gemm_tile64(in_s, w_s, og, lg, acc);
  }
  #pragma unroll
  for (int j = 0; j < 4; j++){
    int o = o0 + j * 16 + og;
    float bias = b2[o];
    #pragma unroll
    for (int i = 0; i < 4; i++){
      int gl = l0 + i * 16 + lg;
      size_t idx = ((size_t)b * 128 + o) * L + gl;
      outp[idx] = acc[j][i] + bias + x2[idx];
    }
  }
}

} // namespace

extern "C" void kernel_launch(void* const* d_in, const int* in_sizes, int n_in,
                              void* d_out, int out_size, void* d_ws, size_t ws_size,
                              hipStream_t stream)
{
  const float* x      = (const float*)d_in[0];
  const float* ln1_g  = (const float*)d_in[1];
  const float* ln1_b  = (const float*)d_in[2];
  const float* q_dw   = (const float*)d_in[3];
  const float* q_bng  = (const float*)d_in[4];
  const float* q_bnb  = (const float*)d_in[5];
  const float* q_bnm  = (const float*)d_in[6];
  const float* q_bnv  = (const float*)d_in[7];
  const float* q_pw   = (const float*)d_in[8];
  const float* k_dw   = (const float*)d_in[9];
  const float* k_bng  = (const float*)d_in[10];
  const float* k_bnb  = (const float*)d_in[11];
  const float* k_bnm  = (const float*)d_in[12];
  const float* k_bnv  = (const float*)d_in[13];
  const float* k_pw   = (const float*)d_in[14];
  const float* v_dw   = (const float*)d_in[15];
  const float* v_bng  = (const float*)d_in[16];
  const float* v_bnb  = (const float*)d_in[17];
  const float* v_bnm  = (const float*)d_in[18];
  const float* v_bnv  = (const float*)d_in[19];
  const float* v_pw   = (const float*)d_in[20];
  const float* dwc_dw  = (const float*)d_in[21];
  const float* dwc_bng = (const float*)d_in[22];
  const float* dwc_bnb = (const float*)d_in[23];
  const float* dwc_bnm = (const float*)d_in[24];
  const float* dwc_bnv = (const float*)d_in[25];
  const float* dwc_pw  = (const float*)d_in[26];
  const float* out_w  = (const float*)d_in[27];
  const float* out_b  = (const float*)d_in[28];
  const float* ln2_g  = (const float*)d_in[29];
  const float* ln2_b  = (const float*)d_in[30];
  const float* ff_w1  = (const float*)d_in[31];
  const float* ff_b1  = (const float*)d_in[32];
  const float* ff_w2  = (const float*)d_in[33];
  const float* ff_b2  = (const float*)d_in[34];
  float* out = (float*)d_out;

  // ---- workspace layout with lifetime-based aliasing (total 224 MB + 68 KB) ----
  // [0,64)    qt              (live: qkv .. gateout)
  // [64,128)  kt (qkv..kk) -> outt (gateout..outw) -> hb (ff1..ff2)
  // [128,192) vt              (live: qkv .. gateout)
  // [192,208) xn f32 (ln1..qkv) -> kkb 4MB (kkred..gateout) -> xn2 (ln2..ff1)
  // [208,224) wpk 768KB (wpack..qkv) -> kkp 16MB (kk..kkred) -> x2 (outw..ff2)
  // [224, +68KB) w2T + c2     (prep .. gateout)
  char* w = (char*)d_ws;
  u16*  qt   = (u16*)(w);
  u16*  kt   = (u16*)(w + (64ull  << 20));
  u16*  outt = kt;
  u16*  hb   = kt;
  u16*  vt   = (u16*)(w + (128ull << 20));
  float* xn  = (float*)(w + (192ull << 20));
  float* kkb = xn;
  float* xn2 = xn;
  float* kkp = (float*)(w + (208ull << 20));
  u16*  wpk  = (u16*)(w + (208ull << 20));
  float* x2  = kkp;
  float* w2T = (float*)(w + (224ull << 20));
  float* c2  = (float*)(w + (224ull << 20) + 65536);

  ln_kernel<<<512, 256, 0, stream>>>(x, ln1_g, ln1_b, xn);
  prep_kernel<<<1, 128, 0, stream>>>(dwc_dw, dwc_bng, dwc_bnb, dwc_bnm, dwc_bnv, dwc_pw, w2T, c2);
  wpack_kernel<<<192, 256, 0, stream>>>(q_pw, k_pw, v_pw, wpk);

  QkvArgs qa;
  qa.dw[0] = q_dw;  qa.bng[0] = q_bng; qa.bnb[0] = q_bnb; qa.bnm[0] = q_bnm; qa.bnv[0] = q_bnv; qa.outp[0] = qt;
  qa.dw[1] = k_dw;  qa.bng[1] = k_bng; qa.bnb[1] = k_bnb; qa.bnm[1] = k_bnm; qa.bnv[1] = k_bnv; qa.outp[1] = kt;
  qa.dw[2] = v_dw;  qa.bng[2] = v_bng; qa.bnb[2] = v_bnb; qa.bnm[2] = v_bnm; qa.bnv[2] = v_bnv; qa.outp[2] = vt;
  qkv_fused_kernel<<<dim3(64, 2, 8), 256, 0, stream>>>(xn, wpk, qa);

  softmax_kernel<<<65536, 256, 0, stream>>>(kt);
  kk_kernel<<<dim3(4, 64), 256, 0, stream>>>(qt, kt, kkp);
  kkred_kernel<<<4096, 256, 0, stream>>>(kkp, kkb);
  gateout_kernel<<<dim3(128, 64), 256, 0, stream>>>(qt, vt, kkb, w2T, c2, outt);
  outw_kernel<<<dim3(64, 2, 8), 256, 0, stream>>>(outt, out_w, out_b, x, x2);

  ln_kernel<<<512, 256, 0, stream>>>(x2, ln2_g, ln2_b, xn2);
  ff1_kernel<<<dim3(64, 8, 8), 256, 0, stream>>>(xn2, ff_w1, ff_b1, hb);
  ff2_kernel<<<dim3(64, 2, 8), 256, 0, stream>>>(hb, ff_w2, ff_b2, x2, out);
}

// Round 4
// 681.854 us; speedup vs baseline: 4.6964x; 2.4719x over previous
//
#include <hip/hip_runtime.h>
#include <hip/hip_bf16.h>
#include <math.h>

#define DI __device__ __forceinline__

namespace {

constexpr int L = 4096;
constexpr float EPS = 1e-5f;
constexpr float SCALEF = 0.08838834764831845f;  // 128^-0.5

typedef unsigned short u16;
typedef unsigned int u32;
typedef __attribute__((ext_vector_type(8))) short bf16x8;
typedef __attribute__((ext_vector_type(4))) float f32x4;

DI float b2f(u16 h){ u32 u = ((u32)h) << 16; float f; __builtin_memcpy(&f, &u, 4); return f; }
DI u16 f2b(float f){ u32 u; __builtin_memcpy(&u, &f, 4); u32 r = u + 0x7fffu + ((u >> 16) & 1u); return (u16)(r >> 16); }
DI float sigmoidf(float x){ return 1.f / (1.f + __expf(-x)); }

// B-frag packed tile offset (o = output col 0..127, d8 = k-chunk 0..15)
DI int boff(int o, int d8){ return ((o >> 4) << 11) + (d8 << 7) + (((o & 15) ^ d8) << 3); }

// stage a 64-row x 128-col bf16 tile (row stride `rs` u16) into A-layout LDS [l][136]
DI void stage_a(const u16* __restrict__ g, int rs, u16* a_s, int tid){
  #pragma unroll
  for (int it = 0; it < 4; it++){
    int item = tid + 256 * it;
    int d8 = item & 15, l = item >> 4;
    *(uint4*)&a_s[l * 136 + d8 * 8] = *(const uint4*)&g[(size_t)l * rs + d8 * 8];
  }
}

// ---------------------------------------------------------------- LN -> bf16 l-major [pos][128]
__global__ __launch_bounds__(256) void ln_kernel(
    const float* __restrict__ x, const float* __restrict__ g,
    const float* __restrict__ bt, u16* __restrict__ o)
{
  const int tid = threadIdx.x;
  const int pos = blockIdx.x * 64 + (tid >> 2);
  const int part = tid & 3;
  const int b = pos >> 12, l = pos & (L - 1);
  const float* xb = x + (size_t)b * 128 * L + l;
  float vv[32];
  float s = 0.f, ss = 0.f;
  #pragma unroll
  for (int i = 0; i < 32; i++){
    float v = xb[(size_t)(part * 32 + i) * L];
    vv[i] = v; s += v; ss += v * v;
  }
  s += __shfl_xor(s, 1);  s += __shfl_xor(s, 2);
  ss += __shfl_xor(ss, 1); ss += __shfl_xor(ss, 2);
  const float m = s * (1.f / 128.f);
  const float rs = rsqrtf(ss * (1.f / 128.f) - m * m + EPS);
  #pragma unroll
  for (int c = 0; c < 4; c++){
    u16 pk[8];
    #pragma unroll
    for (int j = 0; j < 8; j++){
      int d = part * 32 + c * 8 + j;
      pk[j] = f2b((vv[c * 8 + j] - m) * rs * g[d] + bt[d]);
    }
    uint4 uu; __builtin_memcpy(&uu, pk, 16);
    *(uint4*)&o[(size_t)pos * 128 + part * 32 + c * 8] = uu;
  }
}

// ---------------------------------------------------------------- pack all weights to bf16 B-frag tiles
// tiles: 0-23 qkv (p=t/8,h=t%8), 24-31 out_w (h), 32-35 ff_w1 (fc), 36-39 ff_w2 (kc)
__global__ __launch_bounds__(256) void wpack_kernel(
    const float* __restrict__ q_pw, const float* __restrict__ k_pw,
    const float* __restrict__ v_pw, const float* __restrict__ out_w,
    const float* __restrict__ ff_w1, const float* __restrict__ ff_w2,
    u16* __restrict__ wpk)
{
  int item = blockIdx.x * 256 + threadIdx.x;   // 40*2048
  int d8 = item & 15;
  int o  = (item >> 4) & 127;
  int t  = item >> 11;
  const float* src;
  if (t < 24){
    int p = t >> 3, h = t & 7;
    const float* pw = (p == 0) ? q_pw : (p == 1 ? k_pw : v_pw);
    src = pw + (size_t)(h * 128 + o) * 128 + d8 * 8;
  } else if (t < 32){
    src = out_w + (size_t)o * 1024 + (t - 24) * 128 + d8 * 8;
  } else if (t < 36){
    src = ff_w1 + (size_t)((t - 32) * 128 + o) * 128 + d8 * 8;
  } else {
    src = ff_w2 + (size_t)o * 512 + (t - 36) * 128 + d8 * 8;
  }
  u16 pk[8];
  #pragma unroll
  for (int j = 0; j < 8; j++) pk[j] = f2b(src[j]);
  uint4 uu; __builtin_memcpy(&uu, pk, 16);
  *(uint4*)&wpk[(size_t)t * 16384 + boff(o, d8)] = uu;
}

// ---------------------------------------------------------------- fused qkv: dwconv+BN -> MFMA -> bf16 l-major per head
struct QkvArgs {
  const float* dw[3];
  const float* bng[3];
  const float* bnb[3];
  const float* bnm[3];
  const float* bnv[3];
  u16* outp[3];
};

__global__ __launch_bounds__(256, 3) void qkv_fused_kernel(
    const u16* __restrict__ xnb, const u16* __restrict__ wpk, QkvArgs args)
{
  __shared__ u16 y_s[64 * 136];      // A tile
  __shared__ u16 w_s[128 * 128];     // B tile; aliased as out-stage st[64*136]
  __shared__ float4 coef[128];
  const int tid = threadIdx.x;
  const int lb = blockIdx.x;   // 0..63
  const int oh = blockIdx.y;   // 0..1
  const int b  = blockIdx.z;   // 0..7
  const int l0 = lb * 64;
  const int lane = tid & 63, wv = tid >> 6;
  const int nn = lane & 15, quad = lane >> 4;
  const int d8s = tid & 15;

  for (int p = 0; p < 3; p++){
    __syncthreads();   // y_s/coef free from previous iteration
    if (tid < 128){
      int d = tid;
      float sD = args.bng[p][d] * rsqrtf(args.bnv[p][d] + EPS);
      const float* dw = args.dw[p];
      coef[d] = make_float4(dw[d * 3] * sD, dw[d * 3 + 1] * sD, dw[d * 3 + 2] * sD,
                            args.bnb[p][d] - args.bnm[p][d] * sD);
    }
    __syncthreads();
    float4 cf[8];
    #pragma unroll
    for (int jj = 0; jj < 8; jj++) cf[jj] = coef[d8s * 8 + jj];
    #pragma unroll
    for (int it = 0; it < 4; it++){
      int l = (tid >> 4) + it * 16;
      int gl = l0 + l;
      const u16* rowp = xnb + ((size_t)b * L + gl) * 128 + d8s * 8;
      uint4 uc = *(const uint4*)rowp;
      uint4 um = (gl > 0)     ? *(const uint4*)(rowp - 128) : make_uint4(0, 0, 0, 0);
      uint4 up = (gl < L - 1) ? *(const uint4*)(rowp + 128) : make_uint4(0, 0, 0, 0);
      u16 em[8], ec[8], ep[8];
      __builtin_memcpy(em, &um, 16); __builtin_memcpy(ec, &uc, 16); __builtin_memcpy(ep, &up, 16);
      u16 pk[8];
      #pragma unroll
      for (int jj = 0; jj < 8; jj++)
        pk[jj] = f2b(cf[jj].x * b2f(em[jj]) + cf[jj].y * b2f(ec[jj]) + cf[jj].z * b2f(ep[jj]) + cf[jj].w);
      uint4 uu; __builtin_memcpy(&uu, pk, 16);
      *(uint4*)&y_s[l * 136 + d8s * 8] = uu;
    }
    __syncthreads();
    bf16x8 af[4];
    #pragma unroll
    for (int dc = 0; dc < 4; dc++)
      af[dc] = *(const bf16x8*)&y_s[(wv * 16 + nn) * 136 + ((dc << 2) + quad) * 8];

    for (int hh = 0; hh < 4; hh++){
      const int h = oh * 4 + hh;
      const int ph = p * 8 + h;
      __syncthreads();   // w_s free (prior st readers done)
      const u16* src = wpk + ((size_t)ph << 14);
      #pragma unroll
      for (int it = 0; it < 8; it++){
        int idx = (tid + 256 * it) << 3;
        *(uint4*)&w_s[idx] = *(const uint4*)&src[idx];
      }
      __syncthreads();
      f32x4 acc[8];
      #pragma unroll
      for (int os = 0; os < 8; os++) acc[os] = (f32x4){0.f, 0.f, 0.f, 0.f};
      #pragma unroll
      for (int os = 0; os < 8; os++){
        #pragma unroll
        for (int dc = 0; dc < 4; dc++){
          int d8 = (dc << 2) + quad;
          bf16x8 bf = *(const bf16x8*)&w_s[(os << 11) + (d8 << 7) + ((nn ^ d8) << 3)];
          acc[os] = __builtin_amdgcn_mfma_f32_16x16x32_bf16(af[dc], bf, acc[os], 0, 0, 0);
        }
      }
      __syncthreads();   // w_s reads done -> reuse as st
      u16* st = w_s;
      #pragma unroll
      for (int os = 0; os < 8; os++)
        #pragma unroll
        for (int r = 0; r < 4; r++)
          st[(wv * 16 + quad * 4 + r) * 136 + (os << 4) + nn] = f2b(acc[os][r]);
      __syncthreads();
      size_t gbase = ((size_t)(b * 8 + h) * L + l0) * 128;
      u16* outp = args.outp[p];
      #pragma unroll
      for (int it = 0; it < 4; it++){
        int row = (tid >> 4) + (it << 4);
        int c16 = tid & 15;
        *(uint4*)&outp[gbase + (size_t)row * 128 + (c16 << 3)] =
            *(const uint4*)&st[row * 136 + (c16 << 3)];
      }
    }
  }
}

// ---------------------------------------------------------------- softmax over d (rows of 128), in-place bf16
__global__ __launch_bounds__(256) void softmax_kernel(u16* __restrict__ kt)
{
  const int row = blockIdx.x * 4 + (threadIdx.x >> 6);
  const int lane = threadIdx.x & 63;
  u16* r = kt + (size_t)row * 128;
  float v0 = b2f(r[lane]), v1 = b2f(r[lane + 64]);
  float mx = fmaxf(v0, v1);
  #pragma unroll
  for (int o = 32; o; o >>= 1) mx = fmaxf(mx, __shfl_xor(mx, o));
  float e0 = __expf(v0 - mx), e1 = __expf(v1 - mx);
  float s = e0 + e1;
  #pragma unroll
  for (int o = 32; o; o >>= 1) s += __shfl_xor(s, o);
  float inv = 1.f / s;
  r[lane] = f2b(e0 * inv);
  r[lane + 64] = f2b(e1 * inv);
}

// ---------------------------------------------------------------- prep: w2T bf16 B-frag + c2 f32
__global__ void prep_kernel(const float* __restrict__ dwc_dw, const float* __restrict__ g,
                            const float* __restrict__ bb, const float* __restrict__ m,
                            const float* __restrict__ v, const float* __restrict__ pw,
                            u16* __restrict__ w2tb, float* __restrict__ c2)
{
  int e = threadIdx.x;  // 128 threads
  if (e < 128){
    float cacc = 0.f;
    for (int d = 0; d < 128; d++){
      float s = g[d] * rsqrtf(v[d] + EPS);
      float wv = pw[e * 128 + d];
      w2tb[boff(e, d >> 3) + (d & 7)] = f2b(wv * dwc_dw[d] * s);
      cacc += wv * (bb[d] - m[d] * s);
    }
    c2[e] = cacc;
  }
}

// ---------------------------------------------------------------- kk partials (f32 VALU, unchanged)
__global__ __launch_bounds__(256, 2) void kk_kernel(
    const u16* __restrict__ qt, const u16* __restrict__ kt,
    float* __restrict__ kkp)
{
  __shared__ float q_s[32][132];
  __shared__ float k_s[32][132];
  const int tid = threadIdx.x;
  const int sp = blockIdx.x;   // 0..3
  const int n  = blockIdx.y;
  const int x0 = sp * 1024;
  const int dg = tid >> 4, eg = tid & 15;
  float acc[8][8] = {};
  for (int c = 0; c < 32; c++){
    __syncthreads();
    #pragma unroll
    for (int i = 0; i < 16; i++){
      int idx = tid + 256 * i;           // 32*128
      int xx = idx >> 7, d = idx & 127;
      size_t gidx = ((size_t)n * L + x0 + c * 32 + xx) * 128 + d;
      q_s[xx][d] = b2f(qt[gidx]);
      k_s[xx][d] = b2f(kt[gidx]);
    }
    __syncthreads();
    #pragma unroll 4
    for (int xx = 0; xx < 32; xx++){
      float4 q0 = *(const float4*)&q_s[xx][dg * 8];
      float4 q1 = *(const float4*)&q_s[xx][dg * 8 + 4];
      float4 k0 = *(const float4*)&k_s[xx][eg * 8];
      float4 k1 = *(const float4*)&k_s[xx][eg * 8 + 4];
      float qf[8] = {q0.x,q0.y,q0.z,q0.w,q1.x,q1.y,q1.z,q1.w};
      float kf[8] = {k0.x,k0.y,k0.z,k0.w,k1.x,k1.y,k1.z,k1.w};
      #pragma unroll
      for (int a = 0; a < 8; a++)
        #pragma unroll
        for (int e = 0; e < 8; e++)
          acc[a][e] += qf[a] * kf[e];
    }
  }
  float* op = kkp + (((size_t)sp * 64 + n) << 14);
  #pragma unroll
  for (int a = 0; a < 8; a++){
    *(float4*)&op[(dg * 8 + a) * 128 + eg * 8]     = make_float4(acc[a][0], acc[a][1], acc[a][2], acc[a][3]);
    *(float4*)&op[(dg * 8 + a) * 128 + eg * 8 + 4] = make_float4(acc[a][4], acc[a][5], acc[a][6], acc[a][7]);
  }
}

// ---------------------------------------------------------------- kk reduce + scale + pack to bf16 B-frag
__global__ __launch_bounds__(256) void kkred_kernel(
    const float* __restrict__ kkp, u16* __restrict__ kkbb)
{
  int item = blockIdx.x * 256 + threadIdx.x;   // 64n * 16 d8 * 128 e
  int e  = item & 127;
  int d8 = (item >> 7) & 15;
  int n  = item >> 11;
  u16 pk[8];
  #pragma unroll
  for (int j = 0; j < 8; j++){
    float s = 0.f;
    #pragma unroll
    for (int sp = 0; sp < 4; sp++)
      s += kkp[(size_t)sp * (64 * 16384) + n * 16384 + (d8 * 8 + j) * 128 + e];
    pk[j] = f2b(s * SCALEF);
  }
  uint4 uu; __builtin_memcpy(&uu, pk, 16);
  *(uint4*)&kkbb[(size_t)n * 16384 + boff(e, d8)] = uu;
}

// ---------------------------------------------------------------- gateout: MFMA (out = V*kk, gate = Q*w2T)
__global__ __launch_bounds__(256, 3) void gateout_kernel(
    const u16* __restrict__ qt, const u16* __restrict__ vt,
    const u16* __restrict__ kkbb, const u16* __restrict__ w2tb,
    const float* __restrict__ c2, u16* __restrict__ outt)
{
  __shared__ u16 q_s[64 * 136];   // also out-stage st
  __shared__ u16 v_s[64 * 136];
  const int tid = threadIdx.x;
  const int lb = blockIdx.x;   // 0..63
  const int n  = blockIdx.y;   // 0..63
  const int l0 = lb * 64;
  const int lane = tid & 63, wv = tid >> 6;
  const int nn = lane & 15, quad = lane >> 4;
  const size_t base = ((size_t)n * L + l0) * 128;

  stage_a(qt + base, 128, q_s, tid);
  stage_a(vt + base, 128, v_s, tid);
  __syncthreads();

  bf16x8 af_q[4], af_v[4];
  #pragma unroll
  for (int dc = 0; dc < 4; dc++){
    af_q[dc] = *(const bf16x8*)&q_s[(wv * 16 + nn) * 136 + ((dc << 2) + quad) * 8];
    af_v[dc] = *(const bf16x8*)&v_s[(wv * 16 + nn) * 136 + ((dc << 2) + quad) * 8];
  }
  const u16* kb = kkbb + ((size_t)n << 14);
  f32x4 acc_o[8], acc_g[8];
  #pragma unroll
  for (int os = 0; os < 8; os++){ acc_o[os] = (f32x4){0,0,0,0}; acc_g[os] = (f32x4){0,0,0,0}; }
  #pragma unroll
  for (int os = 0; os < 8; os++){
    #pragma unroll
    for (int dc = 0; dc < 4; dc++){
      int d8 = (dc << 2) + quad;
      int off = (os << 11) + (d8 << 7) + ((nn ^ d8) << 3);
      bf16x8 bkk = *(const bf16x8*)&kb[off];
      bf16x8 bw  = *(const bf16x8*)&w2tb[off];
      acc_o[os] = __builtin_amdgcn_mfma_f32_16x16x32_bf16(af_v[dc], bkk, acc_o[os], 0, 0, 0);
      acc_g[os] = __builtin_amdgcn_mfma_f32_16x16x32_bf16(af_q[dc], bw,  acc_g[os], 0, 0, 0);
    }
  }
  __syncthreads();   // q_s reads done -> reuse as st
  u16* st = q_s;
  #pragma unroll
  for (int os = 0; os < 8; os++){
    int e = (os << 4) + nn;
    float c2v = c2[e];
    #pragma unroll
    for (int r = 0; r < 4; r++){
      int xr = wv * 16 + quad * 4 + r;
      float ve = b2f(v_s[xr * 136 + e]);
      float val = acc_o[os][r] + sigmoidf(acc_g[os][r] + c2v) * ve;
      st[xr * 136 + e] = f2b(val);
    }
  }
  __syncthreads();
  #pragma unroll
  for (int it = 0; it < 4; it++){
    int row = (tid >> 4) + (it << 4);
    int c16 = tid & 15;
    *(uint4*)&outt[base + (size_t)row * 128 + (c16 << 3)] =
        *(const uint4*)&st[row * 136 + (c16 << 3)];
  }
}

// ---------------------------------------------------------------- outw: MFMA over 8 head-chunks + bias + residual
__global__ __launch_bounds__(256, 4) void outw_kernel(
    const u16* __restrict__ outt, const u16* __restrict__ wpk,
    const float* __restrict__ out_b, const float* __restrict__ x,
    float* __restrict__ x2)
{
  __shared__ u16 a_s[64 * 136];
  __shared__ float st[64 * 68];
  const int tid = threadIdx.x;
  const int lb = blockIdx.x;   // 64
  const int b  = blockIdx.y;   // 8
  const int l0 = lb * 64;
  const int lane = tid & 63, wv = tid >> 6;
  const int nn = lane & 15, quad = lane >> 4;
  f32x4 acc[8];
  #pragma unroll
  for (int os = 0; os < 8; os++) acc[os] = (f32x4){0,0,0,0};

  for (int h = 0; h < 8; h++){
    __syncthreads();
    stage_a(outt + ((size_t)(b * 8 + h) * L + l0) * 128, 128, a_s, tid);
    __syncthreads();
    bf16x8 af[4];
    #pragma unroll
    for (int dc = 0; dc < 4; dc++)
      af[dc] = *(const bf16x8*)&a_s[(wv * 16 + nn) * 136 + ((dc << 2) + quad) * 8];
    const u16* bp = wpk + (size_t)(24 + h) * 16384;
    #pragma unroll
    for (int os = 0; os < 8; os++){
      #pragma unroll
      for (int dc = 0; dc < 4; dc++){
        int d8 = (dc << 2) + quad;
        bf16x8 bf = *(const bf16x8*)&bp[(os << 11) + (d8 << 7) + ((nn ^ d8) << 3)];
        acc[os] = __builtin_amdgcn_mfma_f32_16x16x32_bf16(af[dc], bf, acc[os], 0, 0, 0);
      }
    }
  }
  // epilogue: two passes of 64 channels via f32 LDS transpose
  #pragma unroll
  for (int t = 0; t < 2; t++){
    __syncthreads();
    #pragma unroll
    for (int osl = 0; osl < 4; osl++){
      int os = t * 4 + osl;
      #pragma unroll
      for (int r = 0; r < 4; r++)
        st[((osl << 4) + nn) * 68 + wv * 16 + quad * 4 + r] = acc[os][r];
    }
    __syncthreads();
    int ol = tid >> 2;                 // 0..63
    int o  = t * 64 + ol;
    int lc = (tid & 3) * 16;
    float bias = out_b[o];
    size_t gbase = ((size_t)b * 128 + o) * L + l0 + lc;
    #pragma unroll
    for (int k = 0; k < 4; k++){
      float4 sv = *(const float4*)&st[ol * 68 + lc + k * 4];
      float4 xv = *(const float4*)&x[gbase + k * 4];
      float4 ov = make_float4(sv.x + bias + xv.x, sv.y + bias + xv.y,
                              sv.z + bias + xv.z, sv.w + bias + xv.w);
      *(float4*)&x2[gbase + k * 4] = ov;
    }
  }
}

// ---------------------------------------------------------------- ff1: MFMA + exact gelu -> hb l-major [b][l][512]
__global__ __launch_bounds__(256, 4) void ff1_kernel(
    const u16* __restrict__ xn2b, const u16* __restrict__ wpk,
    const float* __restrict__ b1, u16* __restrict__ hb)
{
  __shared__ u16 a_s[64 * 136];    // also out-stage st
  const int tid = threadIdx.x;
  const int lb = blockIdx.x;   // 64
  const int fb = blockIdx.y;   // 4
  const int b  = blockIdx.z;   // 8
  const int l0 = lb * 64;
  const int lane = tid & 63, wv = tid >> 6;
  const int nn = lane & 15, quad = lane >> 4;

  stage_a(xn2b + ((size_t)b * L + l0) * 128, 128, a_s, tid);
  __syncthreads();
  bf16x8 af[4];
  #pragma unroll
  for (int dc = 0; dc < 4; dc++)
    af[dc] = *(const bf16x8*)&a_s[(wv * 16 + nn) * 136 + ((dc << 2) + quad) * 8];
  const u16* bp = wpk + (size_t)(32 + fb) * 16384;
  f32x4 acc[8];
  #pragma unroll
  for (int os = 0; os < 8; os++) acc[os] = (f32x4){0,0,0,0};
  #pragma unroll
  for (int os = 0; os < 8; os++){
    #pragma unroll
    for (int dc = 0; dc < 4; dc++){
      int d8 = (dc << 2) + quad;
      bf16x8 bf = *(const bf16x8*)&bp[(os << 11) + (d8 << 7) + ((nn ^ d8) << 3)];
      acc[os] = __builtin_amdgcn_mfma_f32_16x16x32_bf16(af[dc], bf, acc[os], 0, 0, 0);
    }
  }
  __syncthreads();   // a_s reads done -> st
  u16* st = a_s;
  #pragma unroll
  for (int os = 0; os < 8; os++){
    float bias = b1[fb * 128 + (os << 4) + nn];
    #pragma unroll
    for (int r = 0; r < 4; r++){
      float v = acc[os][r] + bias;
      float ge = 0.5f * v * (1.f + erff(v * 0.70710678118654752f));
      st[(wv * 16 + quad * 4 + r) * 136 + (os << 4) + nn] = f2b(ge);
    }
  }
  __syncthreads();
  #pragma unroll
  for (int it = 0; it < 4; it++){
    int row = (tid >> 4) + (it << 4);
    int c16 = tid & 15;
    *(uint4*)&hb[((size_t)b * L + l0 + row) * 512 + fb * 128 + (c16 << 3)] =
        *(const uint4*)&st[row * 136 + (c16 << 3)];
  }
}

// ---------------------------------------------------------------- ff2: MFMA over 4 f-chunks + bias + residual -> d_out
__global__ __launch_bounds__(256, 4) void ff2_kernel(
    const u16* __restrict__ hb, const u16* __restrict__ wpk,
    const float* __restrict__ b2, const float* __restrict__ x2,
    float* __restrict__ outp)
{
  __shared__ u16 a_s[64 * 136];
  __shared__ float st[64 * 68];
  const int tid = threadIdx.x;
  const int lb = blockIdx.x;   // 64
  const int b  = blockIdx.y;   // 8
  const int l0 = lb * 64;
  const int lane = tid & 63, wv = tid >> 6;
  const int nn = lane & 15, quad = lane >> 4;
  f32x4 acc[8];
  #pragma unroll
  for (int os = 0; os < 8; os++) acc[os] = (f32x4){0,0,0,0};

  for (int kc = 0; kc < 4; kc++){
    __syncthreads();
    stage_a(hb + ((size_t)b * L + l0) * 512 + kc * 128, 512, a_s, tid);
    __syncthreads();
    bf16x8 af[4];
    #pragma unroll
    for (int dc = 0; dc < 4; dc++)
      af[dc] = *(const bf16x8*)&a_s[(wv * 16 + nn) * 136 + ((dc << 2) + quad) * 8];
    const u16* bp = wpk + (size_t)(36 + kc) * 16384;
    #pragma unroll
    for (int os = 0; os < 8; os++){
      #pragma unroll
      for (int dc = 0; dc < 4; dc++){
        int d8 = (dc << 2) + quad;
        bf16x8 bf = *(const bf16x8*)&bp[(os << 11) + (d8 << 7) + ((nn ^ d8) << 3)];
        acc[os] = __builtin_amdgcn_mfma_f32_16x16x32_bf16(af[dc], bf, acc[os], 0, 0, 0);
      }
    }
  }
  #pragma unroll
  for (int t = 0; t < 2; t++){
    __syncthreads();
    #pragma unroll
    for (int osl = 0; osl < 4; osl++){
      int os = t * 4 + osl;
      #pragma unroll
      for (int r = 0; r < 4; r++)
        st[((osl << 4) + nn) * 68 + wv * 16 + quad * 4 + r] = acc[os][r];
    }
    __syncthreads();
    int ol = tid >> 2;
    int o  = t * 64 + ol;
    int lc = (tid & 3) * 16;
    float bias = b2[o];
    size_t gbase = ((size_t)b * 128 + o) * L + l0 + lc;
    #pragma unroll
    for (int k = 0; k < 4; k++){
      float4 sv = *(const float4*)&st[ol * 68 + lc + k * 4];
      float4 xv = *(const float4*)&x2[gbase + k * 4];
      float4 ov = make_float4(sv.x + bias + xv.x, sv.y + bias + xv.y,
                              sv.z + bias + xv.z, sv.w + bias + xv.w);
      *(float4*)&outp[gbase + k * 4] = ov;
    }
  }
}

} // namespace

extern "C" void kernel_launch(void* const* d_in, const int* in_sizes, int n_in,
                              void* d_out, int out_size, void* d_ws, size_t ws_size,
                              hipStream_t stream)
{
  const float* x      = (const float*)d_in[0];
  const float* ln1_g  = (const float*)d_in[1];
  const float* ln1_b  = (const float*)d_in[2];
  const float* q_dw   = (const float*)d_in[3];
  const float* q_bng  = (const float*)d_in[4];
  const float* q_bnb  = (const float*)d_in[5];
  const float* q_bnm  = (const float*)d_in[6];
  const float* q_bnv  = (const float*)d_in[7];
  const float* q_pw   = (const float*)d_in[8];
  const float* k_dw   = (const float*)d_in[9];
  const float* k_bng  = (const float*)d_in[10];
  const float* k_bnb  = (const float*)d_in[11];
  const float* k_bnm  = (const float*)d_in[12];
  const float* k_bnv  = (const float*)d_in[13];
  const float* k_pw   = (const float*)d_in[14];
  const float* v_dw   = (const float*)d_in[15];
  const float* v_bng  = (const float*)d_in[16];
  const float* v_bnb  = (const float*)d_in[17];
  const float* v_bnm  = (const float*)d_in[18];
  const float* v_bnv  = (const float*)d_in[19];
  const float* v_pw   = (const float*)d_in[20];
  const float* dwc_dw  = (const float*)d_in[21];
  const float* dwc_bng = (const float*)d_in[22];
  const float* dwc_bnb = (const float*)d_in[23];
  const float* dwc_bnm = (const float*)d_in[24];
  const float* dwc_bnv = (const float*)d_in[25];
  const float* dwc_pw  = (const float*)d_in[26];
  const float* out_w  = (const float*)d_in[27];
  const float* out_b  = (const float*)d_in[28];
  const float* ln2_g  = (const float*)d_in[29];
  const float* ln2_b  = (const float*)d_in[30];
  const float* ff_w1  = (const float*)d_in[31];
  const float* ff_b1  = (const float*)d_in[32];
  const float* ff_w2  = (const float*)d_in[33];
  const float* ff_b2  = (const float*)d_in[34];
  float* out = (float*)d_out;

  // ---- workspace layout (lifetime-aliased, ~218 MB) ----
  // [0,64M)    qt                 (qkv .. gateout)
  // [64,128M)  kt (qkv..kk) -> outt (gateout..outw) -> hb [b][l][512] (ff1..ff2)
  // [128,192M) vt                 (qkv .. gateout)
  // [192,200M) xnb bf16 (ln1..qkv) -> kkbb 2MB (kkred..gateout) -> xn2b (ln2..ff1)
  // [200,216M) kkp 16MB (kk..kkred) -> x2 16MB (outw..ff2)
  // [216M..)   w2tb 32KB + c2 + wpk 1.25MB (live whole pass)
  char* w = (char*)d_ws;
  u16*  qt   = (u16*)(w);
  u16*  kt   = (u16*)(w + (64ull  << 20));
  u16*  outt = kt;
  u16*  hb   = kt;
  u16*  vt   = (u16*)(w + (128ull << 20));
  u16*  xnb  = (u16*)(w + (192ull << 20));
  u16*  kkbb = xnb;
  u16*  xn2b = xnb;
  float* kkp = (float*)(w + (200ull << 20));
  float* x2  = kkp;
  u16*  w2tb = (u16*)(w + (216ull << 20));
  float* c2  = (float*)(w + (216ull << 20) + 32768);
  u16*  wpk  = (u16*)(w + (216ull << 20) + 65536);

  ln_kernel<<<512, 256, 0, stream>>>(x, ln1_g, ln1_b, xnb);
  prep_kernel<<<1, 128, 0, stream>>>(dwc_dw, dwc_bng, dwc_bnb, dwc_bnm, dwc_bnv, dwc_pw, w2tb, c2);
  wpack_kernel<<<320, 256, 0, stream>>>(q_pw, k_pw, v_pw, out_w, ff_w1, ff_w2, wpk);

  QkvArgs qa;
  qa.dw[0] = q_dw;  qa.bng[0] = q_bng; qa.bnb[0] = q_bnb; qa.bnm[0] = q_bnm; qa.bnv[0] = q_bnv; qa.outp[0] = qt;
  qa.dw[1] = k_dw;  qa.bng[1] = k_bng; qa.bnb[1] = k_bnb; qa.bnm[1] = k_bnm; qa.bnv[1] = k_bnv; qa.outp[1] = kt;
  qa.dw[2] = v_dw;  qa.bng[2] = v_bng; qa.bnb[2] = v_bnb; qa.bnm[2] = v_bnm; qa.bnv[2] = v_bnv; qa.outp[2] = vt;
  qkv_fused_kernel<<<dim3(64, 2, 8), 256, 0, stream>>>(xnb, wpk, qa);

  softmax_kernel<<<65536, 256, 0, stream>>>(kt);
  kk_kernel<<<dim3(4, 64), 256, 0, stream>>>(qt, kt, kkp);
  kkred_kernel<<<512, 256, 0, stream>>>(kkp, kkbb);
  gateout_kernel<<<dim3(64, 64), 256, 0, stream>>>(qt, vt, kkbb, w2tb, c2, outt);
  outw_kernel<<<dim3(64, 8), 256, 0, stream>>>(outt, wpk, out_b, x, x2);

  ln_kernel<<<512, 256, 0, stream>>>(x2, ln2_g, ln2_b, xn2b);
  ff1_kernel<<<dim3(64, 4, 8), 256, 0, stream>>>(xn2b, wpk, ff_b1, hb);
  ff2_kernel<<<dim3(64, 8), 256, 0, stream>>>(hb, wpk, ff_b2, x2, out);
}

// Round 5
// 461.292 us; speedup vs baseline: 6.9419x; 1.4781x over previous
//
#include <hip/hip_runtime.h>
#include <hip/hip_bf16.h>
#include <math.h>

#define DI __device__ __forceinline__

namespace {

constexpr int L = 4096;
constexpr float EPS = 1e-5f;
constexpr float SCALEF = 0.08838834764831845f;  // 128^-0.5

typedef unsigned short u16;
typedef unsigned int u32;
typedef __attribute__((ext_vector_type(8))) short bf16x8;
typedef __attribute__((ext_vector_type(4))) float f32x4;

DI float b2f(u16 h){ u32 u = ((u32)h) << 16; float f; __builtin_memcpy(&f, &u, 4); return f; }
DI u16 f2b(float f){ u32 u; __builtin_memcpy(&u, &f, 4); u32 r = u + 0x7fffu + ((u >> 16) & 1u); return (u16)(r >> 16); }
DI float sigmoidf(float x){ return 1.f / (1.f + __expf(-x)); }

// B-frag packed tile offset (o = output col 0..127, d8 = k-chunk 0..15)
DI int boff(int o, int d8){ return ((o >> 4) << 11) + (d8 << 7) + (((o & 15) ^ d8) << 3); }

// transposed-tile offset for kk staging: element (d, x) at
// (d>>4)<<11 | (x>>3)<<7 | (((d&15) ^ (x>>3) ^ (d>>4)) & 15)<<3 | (x&7)
DI int toff(int dhi, int nl, int x8){ return (dhi << 11) + (x8 << 7) + (((nl ^ x8 ^ dhi) & 15) << 3); }

// stage a 64-row x 128-col bf16 tile (row stride `rs` u16) into A-layout LDS [l][136]
DI void stage_a(const u16* __restrict__ g, int rs, u16* a_s, int tid){
  #pragma unroll
  for (int it = 0; it < 4; it++){
    int item = tid + 256 * it;
    int d8 = item & 15, l = item >> 4;
    *(uint4*)&a_s[l * 136 + d8 * 8] = *(const uint4*)&g[(size_t)l * rs + d8 * 8];
  }
}

// ---------------------------------------------------------------- LN -> bf16 l-major [pos][128]
__global__ __launch_bounds__(256) void ln_kernel(
    const float* __restrict__ x, const float* __restrict__ g,
    const float* __restrict__ bt, u16* __restrict__ o)
{
  const int tid = threadIdx.x;
  const int pos = blockIdx.x * 64 + (tid >> 2);
  const int part = tid & 3;
  const int b = pos >> 12, l = pos & (L - 1);
  const float* xb = x + (size_t)b * 128 * L + l;
  float vv[32];
  float s = 0.f, ss = 0.f;
  #pragma unroll
  for (int i = 0; i < 32; i++){
    float v = xb[(size_t)(part * 32 + i) * L];
    vv[i] = v; s += v; ss += v * v;
  }
  s += __shfl_xor(s, 1);  s += __shfl_xor(s, 2);
  ss += __shfl_xor(ss, 1); ss += __shfl_xor(ss, 2);
  const float m = s * (1.f / 128.f);
  const float rs = rsqrtf(ss * (1.f / 128.f) - m * m + EPS);
  #pragma unroll
  for (int c = 0; c < 4; c++){
    u16 pk[8];
    #pragma unroll
    for (int j = 0; j < 8; j++){
      int d = part * 32 + c * 8 + j;
      pk[j] = f2b((vv[c * 8 + j] - m) * rs * g[d] + bt[d]);
    }
    uint4 uu; __builtin_memcpy(&uu, pk, 16);
    *(uint4*)&o[(size_t)pos * 128 + part * 32 + c * 8] = uu;
  }
}

// ---------------------------------------------------------------- pack all weights to bf16 B-frag tiles
// tiles: 0-23 qkv (p=t/8,h=t%8), 24-31 out_w (h), 32-35 ff_w1 (fc), 36-39 ff_w2 (kc)
__global__ __launch_bounds__(256) void wpack_kernel(
    const float* __restrict__ q_pw, const float* __restrict__ k_pw,
    const float* __restrict__ v_pw, const float* __restrict__ out_w,
    const float* __restrict__ ff_w1, const float* __restrict__ ff_w2,
    u16* __restrict__ wpk)
{
  int item = blockIdx.x * 256 + threadIdx.x;   // 40*2048
  int d8 = item & 15;
  int o  = (item >> 4) & 127;
  int t  = item >> 11;
  const float* src;
  if (t < 24){
    int p = t >> 3, h = t & 7;
    const float* pw = (p == 0) ? q_pw : (p == 1 ? k_pw : v_pw);
    src = pw + (size_t)(h * 128 + o) * 128 + d8 * 8;
  } else if (t < 32){
    src = out_w + (size_t)o * 1024 + (t - 24) * 128 + d8 * 8;
  } else if (t < 36){
    src = ff_w1 + (size_t)((t - 32) * 128 + o) * 128 + d8 * 8;
  } else {
    src = ff_w2 + (size_t)o * 512 + (t - 36) * 128 + d8 * 8;
  }
  u16 pk[8];
  #pragma unroll
  for (int j = 0; j < 8; j++) pk[j] = f2b(src[j]);
  uint4 uu; __builtin_memcpy(&uu, pk, 16);
  *(uint4*)&wpk[(size_t)t * 16384 + boff(o, d8)] = uu;
}

// ---------------------------------------------------------------- fused qkv: dwconv+BN -> MFMA -> bf16 l-major per head
struct QkvArgs {
  const float* dw[3];
  const float* bng[3];
  const float* bnb[3];
  const float* bnm[3];
  const float* bnv[3];
  u16* outp[3];
};

__global__ __launch_bounds__(256, 3) void qkv_fused_kernel(
    const u16* __restrict__ xnb, const u16* __restrict__ wpk, QkvArgs args)
{
  __shared__ u16 y_s[64 * 136];      // A tile
  __shared__ u16 w_s[128 * 128];     // B tile; aliased as out-stage st[64*136]
  __shared__ float4 coef[128];
  const int tid = threadIdx.x;
  const int lb = blockIdx.x;   // 0..63
  const int oh = blockIdx.y;   // 0..1
  const int b  = blockIdx.z;   // 0..7
  const int l0 = lb * 64;
  const int lane = tid & 63, wv = tid >> 6;
  const int nn = lane & 15, quad = lane >> 4;
  const int d8s = tid & 15;

  for (int p = 0; p < 3; p++){
    __syncthreads();   // y_s/coef free from previous iteration
    if (tid < 128){
      int d = tid;
      float sD = args.bng[p][d] * rsqrtf(args.bnv[p][d] + EPS);
      const float* dw = args.dw[p];
      coef[d] = make_float4(dw[d * 3] * sD, dw[d * 3 + 1] * sD, dw[d * 3 + 2] * sD,
                            args.bnb[p][d] - args.bnm[p][d] * sD);
    }
    __syncthreads();
    float4 cf[8];
    #pragma unroll
    for (int jj = 0; jj < 8; jj++) cf[jj] = coef[d8s * 8 + jj];
    #pragma unroll
    for (int it = 0; it < 4; it++){
      int l = (tid >> 4) + it * 16;
      int gl = l0 + l;
      const u16* rowp = xnb + ((size_t)b * L + gl) * 128 + d8s * 8;
      uint4 uc = *(const uint4*)rowp;
      uint4 um = (gl > 0)     ? *(const uint4*)(rowp - 128) : make_uint4(0, 0, 0, 0);
      uint4 up = (gl < L - 1) ? *(const uint4*)(rowp + 128) : make_uint4(0, 0, 0, 0);
      u16 em[8], ec[8], ep[8];
      __builtin_memcpy(em, &um, 16); __builtin_memcpy(ec, &uc, 16); __builtin_memcpy(ep, &up, 16);
      u16 pk[8];
      #pragma unroll
      for (int jj = 0; jj < 8; jj++)
        pk[jj] = f2b(cf[jj].x * b2f(em[jj]) + cf[jj].y * b2f(ec[jj]) + cf[jj].z * b2f(ep[jj]) + cf[jj].w);
      uint4 uu; __builtin_memcpy(&uu, pk, 16);
      *(uint4*)&y_s[l * 136 + d8s * 8] = uu;
    }
    __syncthreads();
    bf16x8 af[4];
    #pragma unroll
    for (int dc = 0; dc < 4; dc++)
      af[dc] = *(const bf16x8*)&y_s[(wv * 16 + nn) * 136 + ((dc << 2) + quad) * 8];

    for (int hh = 0; hh < 4; hh++){
      const int h = oh * 4 + hh;
      const int ph = p * 8 + h;
      __syncthreads();   // w_s free (prior st readers done)
      const u16* src = wpk + ((size_t)ph << 14);
      #pragma unroll
      for (int it = 0; it < 8; it++){
        int idx = (tid + 256 * it) << 3;
        *(uint4*)&w_s[idx] = *(const uint4*)&src[idx];
      }
      __syncthreads();
      f32x4 acc[8];
      #pragma unroll
      for (int os = 0; os < 8; os++) acc[os] = (f32x4){0.f, 0.f, 0.f, 0.f};
      #pragma unroll
      for (int os = 0; os < 8; os++){
        #pragma unroll
        for (int dc = 0; dc < 4; dc++){
          int d8 = (dc << 2) + quad;
          bf16x8 bf = *(const bf16x8*)&w_s[(os << 11) + (d8 << 7) + ((nn ^ d8) << 3)];
          acc[os] = __builtin_amdgcn_mfma_f32_16x16x32_bf16(af[dc], bf, acc[os], 0, 0, 0);
        }
      }
      __syncthreads();   // w_s reads done -> reuse as st
      u16* st = w_s;
      #pragma unroll
      for (int os = 0; os < 8; os++)
        #pragma unroll
        for (int r = 0; r < 4; r++)
          st[(wv * 16 + quad * 4 + r) * 136 + (os << 4) + nn] = f2b(acc[os][r]);
      __syncthreads();
      size_t gbase = ((size_t)(b * 8 + h) * L + l0) * 128;
      u16* outp = args.outp[p];
      #pragma unroll
      for (int it = 0; it < 4; it++){
        int row = (tid >> 4) + (it << 4);
        int c16 = tid & 15;
        *(uint4*)&outp[gbase + (size_t)row * 128 + (c16 << 3)] =
            *(const uint4*)&st[row * 136 + (c16 << 3)];
      }
    }
  }
}

// ---------------------------------------------------------------- softmax over d (rows of 128), in-place bf16
__global__ __launch_bounds__(256) void softmax_kernel(u16* __restrict__ kt)
{
  const int row = blockIdx.x * 4 + (threadIdx.x >> 6);
  const int lane = threadIdx.x & 63;
  u16* r = kt + (size_t)row * 128;
  float v0 = b2f(r[lane]), v1 = b2f(r[lane + 64]);
  float mx = fmaxf(v0, v1);
  #pragma unroll
  for (int o = 32; o; o >>= 1) mx = fmaxf(mx, __shfl_xor(mx, o));
  float e0 = __expf(v0 - mx), e1 = __expf(v1 - mx);
  float s = e0 + e1;
  #pragma unroll
  for (int o = 32; o; o >>= 1) s += __shfl_xor(s, o);
  float inv = 1.f / s;
  r[lane] = f2b(e0 * inv);
  r[lane + 64] = f2b(e1 * inv);
}

// ---------------------------------------------------------------- prep: w2T bf16 B-frag + c2 f32
__global__ void prep_kernel(const float* __restrict__ dwc_dw, const float* __restrict__ g,
                            const float* __restrict__ bb, const float* __restrict__ m,
                            const float* __restrict__ v, const float* __restrict__ pw,
                            u16* __restrict__ w2tb, float* __restrict__ c2)
{
  int e = threadIdx.x;  // 128 threads
  if (e < 128){
    float cacc = 0.f;
    for (int d = 0; d < 128; d++){
      float s = g[d] * rsqrtf(v[d] + EPS);
      float wv = pw[e * 128 + d];
      w2tb[boff(e, d >> 3) + (d & 7)] = f2b(wv * dwc_dw[d] * s);
      cacc += wv * (bb[d] - m[d] * s);
    }
    c2[e] = cacc;
  }
}

// ---------------------------------------------------------------- kk partials via MFMA with in-register transpose
// kk[n][d][e] = sum_x q[x][d] * ks[x][e]; grid (4 sp, 64 n), K=1024 per block.
__global__ __launch_bounds__(256, 2) void kk_kernel(
    const u16* __restrict__ qt, const u16* __restrict__ kt,
    float* __restrict__ kkp)
{
  __shared__ u16 qT[16384];   // 32 KB, transposed swizzled [d][x] tile (128x128)
  __shared__ u16 kT[16384];   // 32 KB
  const int tid = threadIdx.x;
  const int sp = blockIdx.x;   // 0..3
  const int n  = blockIdx.y;   // 0..63
  const int d8 = tid & 15;     // col-chunk (d8*8..+7), keeps global reads row-coalesced
  const int x8 = tid >> 4;     // row-group (x8*8..+7)
  const int lane = tid & 63, wv = tid >> 6;
  const int nn = lane & 15, quad = lane >> 4;
  const int m4 = (wv >> 1) << 2;   // d>>4 base (0 or 4)
  const int e4 = (wv & 1) << 2;    // e>>4 base
  const size_t gbase = ((size_t)n * L + sp * 1024) * 128;

  uint4 rq[8], rk[8];
  #pragma unroll
  for (int j = 0; j < 8; j++){
    size_t off = gbase + (size_t)(x8 * 8 + j) * 128 + d8 * 8;
    rq[j] = *(const uint4*)&qt[off];
    rk[j] = *(const uint4*)&kt[off];
  }

  f32x4 acc[4][4];
  #pragma unroll
  for (int mi = 0; mi < 4; mi++)
    #pragma unroll
    for (int ei = 0; ei < 4; ei++) acc[mi][ei] = (f32x4){0.f, 0.f, 0.f, 0.f};

  for (int c = 0; c < 8; c++){
    // in-register 8x8 transpose, write b128 into swizzled [d][x] tiles
    #pragma unroll
    for (int i = 0; i < 8; i++){
      u16 cq[8], ck[8];
      #pragma unroll
      for (int j = 0; j < 8; j++){
        u16 tmp[8];
        __builtin_memcpy(tmp, &rq[j], 16); cq[j] = tmp[i];
        __builtin_memcpy(tmp, &rk[j], 16); ck[j] = tmp[i];
      }
      int off = toff(d8 >> 1, ((d8 & 1) << 3) + i, x8);
      uint4 uq, uk;
      __builtin_memcpy(&uq, cq, 16); __builtin_memcpy(&uk, ck, 16);
      *(uint4*)&qT[off] = uq;
      *(uint4*)&kT[off] = uk;
    }
    __syncthreads();
    if (c < 7){   // prefetch next chunk, overlaps MFMA phase
      #pragma unroll
      for (int j = 0; j < 8; j++){
        size_t off = gbase + (size_t)((c + 1) * 128 + x8 * 8 + j) * 128 + d8 * 8;
        rq[j] = *(const uint4*)&qt[off];
        rk[j] = *(const uint4*)&kt[off];
      }
    }
    #pragma unroll
    for (int ks = 0; ks < 4; ks++){
      int x8f = (ks << 2) + quad;
      bf16x8 af[4], bf[4];
      #pragma unroll
      for (int t = 0; t < 4; t++){
        af[t] = *(const bf16x8*)&qT[toff(m4 + t, nn, x8f)];
        bf[t] = *(const bf16x8*)&kT[toff(e4 + t, nn, x8f)];
      }
      #pragma unroll
      for (int mi = 0; mi < 4; mi++)
        #pragma unroll
        for (int ei = 0; ei < 4; ei++)
          acc[mi][ei] = __builtin_amdgcn_mfma_f32_16x16x32_bf16(af[mi], bf[ei], acc[mi][ei], 0, 0, 0);
    }
    __syncthreads();
  }

  float* op = kkp + ((size_t)(sp * 64 + n) << 14);
  #pragma unroll
  for (int mi = 0; mi < 4; mi++){
    #pragma unroll
    for (int r = 0; r < 4; r++){
      int d = (m4 << 4) + mi * 16 + quad * 4 + r;
      #pragma unroll
      for (int ei = 0; ei < 4; ei++)
        op[d * 128 + (e4 << 4) + ei * 16 + nn] = acc[mi][ei][r];
    }
  }
}

// ---------------------------------------------------------------- kk reduce + scale + pack to bf16 B-frag
__global__ __launch_bounds__(256) void kkred_kernel(
    const float* __restrict__ kkp, u16* __restrict__ kkbb)
{
  int item = blockIdx.x * 256 + threadIdx.x;   // 64n * 16 d8 * 128 e
  int e  = item & 127;
  int d8 = (item >> 7) & 15;
  int n  = item >> 11;
  u16 pk[8];
  #pragma unroll
  for (int j = 0; j < 8; j++){
    float s = 0.f;
    #pragma unroll
    for (int sp = 0; sp < 4; sp++)
      s += kkp[(size_t)sp * (64 * 16384) + n * 16384 + (d8 * 8 + j) * 128 + e];
    pk[j] = f2b(s * SCALEF);
  }
  uint4 uu; __builtin_memcpy(&uu, pk, 16);
  *(uint4*)&kkbb[(size_t)n * 16384 + boff(e, d8)] = uu;
}

// ---------------------------------------------------------------- gateout: MFMA (out = V*kk, gate = Q*w2T)
__global__ __launch_bounds__(256, 3) void gateout_kernel(
    const u16* __restrict__ qt, const u16* __restrict__ vt,
    const u16* __restrict__ kkbb, const u16* __restrict__ w2tb,
    const float* __restrict__ c2, u16* __restrict__ outt)
{
  __shared__ u16 q_s[64 * 136];   // also out-stage st
  __shared__ u16 v_s[64 * 136];
  const int tid = threadIdx.x;
  const int lb = blockIdx.x;   // 0..63
  const int n  = blockIdx.y;   // 0..63
  const int l0 = lb * 64;
  const int lane = tid & 63, wv = tid >> 6;
  const int nn = lane & 15, quad = lane >> 4;
  const size_t base = ((size_t)n * L + l0) * 128;

  stage_a(qt + base, 128, q_s, tid);
  stage_a(vt + base, 128, v_s, tid);
  __syncthreads();

  bf16x8 af_q[4], af_v[4];
  #pragma unroll
  for (int dc = 0; dc < 4; dc++){
    af_q[dc] = *(const bf16x8*)&q_s[(wv * 16 + nn) * 136 + ((dc << 2) + quad) * 8];
    af_v[dc] = *(const bf16x8*)&v_s[(wv * 16 + nn) * 136 + ((dc << 2) + quad) * 8];
  }
  const u16* kb = kkbb + ((size_t)n << 14);
  f32x4 acc_o[8], acc_g[8];
  #pragma unroll
  for (int os = 0; os < 8; os++){ acc_o[os] = (f32x4){0,0,0,0}; acc_g[os] = (f32x4){0,0,0,0}; }
  #pragma unroll
  for (int os = 0; os < 8; os++){
    #pragma unroll
    for (int dc = 0; dc < 4; dc++){
      int d8 = (dc << 2) + quad;
      int off = (os << 11) + (d8 << 7) + ((nn ^ d8) << 3);
      bf16x8 bkk = *(const bf16x8*)&kb[off];
      bf16x8 bw  = *(const bf16x8*)&w2tb[off];
      acc_o[os] = __builtin_amdgcn_mfma_f32_16x16x32_bf16(af_v[dc], bkk, acc_o[os], 0, 0, 0);
      acc_g[os] = __builtin_amdgcn_mfma_f32_16x16x32_bf16(af_q[dc], bw,  acc_g[os], 0, 0, 0);
    }
  }
  __syncthreads();   // q_s reads done -> reuse as st
  u16* st = q_s;
  #pragma unroll
  for (int os = 0; os < 8; os++){
    int e = (os << 4) + nn;
    float c2v = c2[e];
    #pragma unroll
    for (int r = 0; r < 4; r++){
      int xr = wv * 16 + quad * 4 + r;
      float ve = b2f(v_s[xr * 136 + e]);
      float val = acc_o[os][r] + sigmoidf(acc_g[os][r] + c2v) * ve;
      st[xr * 136 + e] = f2b(val);
    }
  }
  __syncthreads();
  #pragma unroll
  for (int it = 0; it < 4; it++){
    int row = (tid >> 4) + (it << 4);
    int c16 = tid & 15;
    *(uint4*)&outt[base + (size_t)row * 128 + (c16 << 3)] =
        *(const uint4*)&st[row * 136 + (c16 << 3)];
  }
}

// ---------------------------------------------------------------- outw: MFMA over 8 head-chunks + bias + residual
__global__ __launch_bounds__(256, 4) void outw_kernel(
    const u16* __restrict__ outt, const u16* __restrict__ wpk,
    const float* __restrict__ out_b, const float* __restrict__ x,
    float* __restrict__ x2)
{
  __shared__ u16 a_s[64 * 136];
  __shared__ float st[64 * 68];
  const int tid = threadIdx.x;
  const int lb = blockIdx.x;   // 64
  const int b  = blockIdx.y;   // 8
  const int l0 = lb * 64;
  const int lane = tid & 63, wv = tid >> 6;
  const int nn = lane & 15, quad = lane >> 4;
  f32x4 acc[8];
  #pragma unroll
  for (int os = 0; os < 8; os++) acc[os] = (f32x4){0,0,0,0};

  for (int h = 0; h < 8; h++){
    __syncthreads();
    stage_a(outt + ((size_t)(b * 8 + h) * L + l0) * 128, 128, a_s, tid);
    __syncthreads();
    bf16x8 af[4];
    #pragma unroll
    for (int dc = 0; dc < 4; dc++)
      af[dc] = *(const bf16x8*)&a_s[(wv * 16 + nn) * 136 + ((dc << 2) + quad) * 8];
    const u16* bp = wpk + (size_t)(24 + h) * 16384;
    #pragma unroll
    for (int os = 0; os < 8; os++){
      #pragma unroll
      for (int dc = 0; dc < 4; dc++){
        int d8 = (dc << 2) + quad;
        bf16x8 bf = *(const bf16x8*)&bp[(os << 11) + (d8 << 7) + ((nn ^ d8) << 3)];
        acc[os] = __builtin_amdgcn_mfma_f32_16x16x32_bf16(af[dc], bf, acc[os], 0, 0, 0);
      }
    }
  }
  // epilogue: two passes of 64 channels via f32 LDS transpose
  #pragma unroll
  for (int t = 0; t < 2; t++){
    __syncthreads();
    #pragma unroll
    for (int osl = 0; osl < 4; osl++){
      int os = t * 4 + osl;
      #pragma unroll
      for (int r = 0; r < 4; r++)
        st[((osl << 4) + nn) * 68 + wv * 16 + quad * 4 + r] = acc[os][r];
    }
    __syncthreads();
    int ol = tid >> 2;                 // 0..63
    int o  = t * 64 + ol;
    int lc = (tid & 3) * 16;
    float bias = out_b[o];
    size_t gbase = ((size_t)b * 128 + o) * L + l0 + lc;
    #pragma unroll
    for (int k = 0; k < 4; k++){
      float4 sv = *(const float4*)&st[ol * 68 + lc + k * 4];
      float4 xv = *(const float4*)&x[gbase + k * 4];
      float4 ov = make_float4(sv.x + bias + xv.x, sv.y + bias + xv.y,
                              sv.z + bias + xv.z, sv.w + bias + xv.w);
      *(float4*)&x2[gbase + k * 4] = ov;
    }
  }
}

// ---------------------------------------------------------------- ff1: MFMA + exact gelu -> hb l-major [b][l][512]
__global__ __launch_bounds__(256, 4) void ff1_kernel(
    const u16* __restrict__ xn2b, const u16* __restrict__ wpk,
    const float* __restrict__ b1, u16* __restrict__ hb)
{
  __shared__ u16 a_s[64 * 136];    // also out-stage st
  const int tid = threadIdx.x;
  const int lb = blockIdx.x;   // 64
  const int fb = blockIdx.y;   // 4
  const int b  = blockIdx.z;   // 8
  const int l0 = lb * 64;
  const int lane = tid & 63, wv = tid >> 6;
  const int nn = lane & 15, quad = lane >> 4;

  stage_a(xn2b + ((size_t)b * L + l0) * 128, 128, a_s, tid);
  __syncthreads();
  bf16x8 af[4];
  #pragma unroll
  for (int dc = 0; dc < 4; dc++)
    af[dc] = *(const bf16x8*)&a_s[(wv * 16 + nn) * 136 + ((dc << 2) + quad) * 8];
  const u16* bp = wpk + (size_t)(32 + fb) * 16384;
  f32x4 acc[8];
  #pragma unroll
  for (int os = 0; os < 8; os++) acc[os] = (f32x4){0,0,0,0};
  #pragma unroll
  for (int os = 0; os < 8; os++){
    #pragma unroll
    for (int dc = 0; dc < 4; dc++){
      int d8 = (dc << 2) + quad;
      bf16x8 bf = *(const bf16x8*)&bp[(os << 11) + (d8 << 7) + ((nn ^ d8) << 3)];
      acc[os] = __builtin_amdgcn_mfma_f32_16x16x32_bf16(af[dc], bf, acc[os], 0, 0, 0);
    }
  }
  __syncthreads();   // a_s reads done -> st
  u16* st = a_s;
  #pragma unroll
  for (int os = 0; os < 8; os++){
    float bias = b1[fb * 128 + (os << 4) + nn];
    #pragma unroll
    for (int r = 0; r < 4; r++){
      float v = acc[os][r] + bias;
      float ge = 0.5f * v * (1.f + erff(v * 0.70710678118654752f));
      st[(wv * 16 + quad * 4 + r) * 136 + (os << 4) + nn] = f2b(ge);
    }
  }
  __syncthreads();
  #pragma unroll
  for (int it = 0; it < 4; it++){
    int row = (tid >> 4) + (it << 4);
    int c16 = tid & 15;
    *(uint4*)&hb[((size_t)b * L + l0 + row) * 512 + fb * 128 + (c16 << 3)] =
        *(const uint4*)&st[row * 136 + (c16 << 3)];
  }
}

// ---------------------------------------------------------------- ff2: MFMA over 4 f-chunks + bias + residual -> d_out
__global__ __launch_bounds__(256, 4) void ff2_kernel(
    const u16* __restrict__ hb, const u16* __restrict__ wpk,
    const float* __restrict__ b2, const float* __restrict__ x2,
    float* __restrict__ outp)
{
  __shared__ u16 a_s[64 * 136];
  __shared__ float st[64 * 68];
  const int tid = threadIdx.x;
  const int lb = blockIdx.x;   // 64
  const int b  = blockIdx.y;   // 8
  const int l0 = lb * 64;
  const int lane = tid & 63, wv = tid >> 6;
  const int nn = lane & 15, quad = lane >> 4;
  f32x4 acc[8];
  #pragma unroll
  for (int os = 0; os < 8; os++) acc[os] = (f32x4){0,0,0,0};

  for (int kc = 0; kc < 4; kc++){
    __syncthreads();
    stage_a(hb + ((size_t)b * L + l0) * 512 + kc * 128, 512, a_s, tid);
    __syncthreads();
    bf16x8 af[4];
    #pragma unroll
    for (int dc = 0; dc < 4; dc++)
      af[dc] = *(const bf16x8*)&a_s[(wv * 16 + nn) * 136 + ((dc << 2) + quad) * 8];
    const u16* bp = wpk + (size_t)(36 + kc) * 16384;
    #pragma unroll
    for (int os = 0; os < 8; os++){
      #pragma unroll
      for (int dc = 0; dc < 4; dc++){
        int d8 = (dc << 2) + quad;
        bf16x8 bf = *(const bf16x8*)&bp[(os << 11) + (d8 << 7) + ((nn ^ d8) << 3)];
        acc[os] = __builtin_amdgcn_mfma_f32_16x16x32_bf16(af[dc], bf, acc[os], 0, 0, 0);
      }
    }
  }
  #pragma unroll
  for (int t = 0; t < 2; t++){
    __syncthreads();
    #pragma unroll
    for (int osl = 0; osl < 4; osl++){
      int os = t * 4 + osl;
      #pragma unroll
      for (int r = 0; r < 4; r++)
        st[((osl << 4) + nn) * 68 + wv * 16 + quad * 4 + r] = acc[os][r];
    }
    __syncthreads();
    int ol = tid >> 2;
    int o  = t * 64 + ol;
    int lc = (tid & 3) * 16;
    float bias = b2[o];
    size_t gbase = ((size_t)b * 128 + o) * L + l0 + lc;
    #pragma unroll
    for (int k = 0; k < 4; k++){
      float4 sv = *(const float4*)&st[ol * 68 + lc + k * 4];
      float4 xv = *(const float4*)&x2[gbase + k * 4];
      float4 ov = make_float4(sv.x + bias + xv.x, sv.y + bias + xv.y,
                              sv.z + bias + xv.z, sv.w + bias + xv.w);
      *(float4*)&outp[gbase + k * 4] = ov;
    }
  }
}

} // namespace

extern "C" void kernel_launch(void* const* d_in, const int* in_sizes, int n_in,
                              void* d_out, int out_size, void* d_ws, size_t ws_size,
                              hipStream_t stream)
{
  const float* x      = (const float*)d_in[0];
  const float* ln1_g  = (const float*)d_in[1];
  const float* ln1_b  = (const float*)d_in[2];
  const float* q_dw   = (const float*)d_in[3];
  const float* q_bng  = (const float*)d_in[4];
  const float* q_bnb  = (const float*)d_in[5];
  const float* q_bnm  = (const float*)d_in[6];
  const float* q_bnv  = (const float*)d_in[7];
  const float* q_pw   = (const float*)d_in[8];
  const float* k_dw   = (const float*)d_in[9];
  const float* k_bng  = (const float*)d_in[10];
  const float* k_bnb  = (const float*)d_in[11];
  const float* k_bnm  = (const float*)d_in[12];
  const float* k_bnv  = (const float*)d_in[13];
  const float* k_pw   = (const float*)d_in[14];
  const float* v_dw   = (const float*)d_in[15];
  const float* v_bng  = (const float*)d_in[16];
  const float* v_bnb  = (const float*)d_in[17];
  const float* v_bnm  = (const float*)d_in[18];
  const float* v_bnv  = (const float*)d_in[19];
  const float* v_pw   = (const float*)d_in[20];
  const float* dwc_dw  = (const float*)d_in[21];
  const float* dwc_bng = (const float*)d_in[22];
  const float* dwc_bnb = (const float*)d_in[23];
  const float* dwc_bnm = (const float*)d_in[24];
  const float* dwc_bnv = (const float*)d_in[25];
  const float* dwc_pw  = (const float*)d_in[26];
  const float* out_w  = (const float*)d_in[27];
  const float* out_b  = (const float*)d_in[28];
  const float* ln2_g  = (const float*)d_in[29];
  const float* ln2_b  = (const float*)d_in[30];
  const float* ff_w1  = (const float*)d_in[31];
  const float* ff_b1  = (const float*)d_in[32];
  const float* ff_w2  = (const float*)d_in[33];
  const float* ff_b2  = (const float*)d_in[34];
  float* out = (float*)d_out;

  // ---- workspace layout (lifetime-aliased, ~218 MB) ----
  // [0,64M)    qt                 (qkv .. gateout)
  // [64,128M)  kt (qkv..kk) -> outt (gateout..outw) -> hb [b][l][512] (ff1..ff2)
  // [128,192M) vt                 (qkv .. gateout)
  // [192,200M) xnb bf16 (ln1..qkv) -> kkbb 2MB (kkred..gateout) -> xn2b (ln2..ff1)
  // [200,216M) kkp 16MB (kk..kkred) -> x2 16MB (outw..ff2)
  // [216M..)   w2tb 32KB + c2 + wpk 1.25MB (live whole pass)
  char* w = (char*)d_ws;
  u16*  qt   = (u16*)(w);
  u16*  kt   = (u16*)(w + (64ull  << 20));
  u16*  outt = kt;
  u16*  hb   = kt;
  u16*  vt   = (u16*)(w + (128ull << 20));
  u16*  xnb  = (u16*)(w + (192ull << 20));
  u16*  kkbb = xnb;
  u16*  xn2b = xnb;
  float* kkp = (float*)(w + (200ull << 20));
  float* x2  = kkp;
  u16*  w2tb = (u16*)(w + (216ull << 20));
  float* c2  = (float*)(w + (216ull << 20) + 32768);
  u16*  wpk  = (u16*)(w + (216ull << 20) + 65536);

  ln_kernel<<<512, 256, 0, stream>>>(x, ln1_g, ln1_b, xnb);
  prep_kernel<<<1, 128, 0, stream>>>(dwc_dw, dwc_bng, dwc_bnb, dwc_bnm, dwc_bnv, dwc_pw, w2tb, c2);
  wpack_kernel<<<320, 256, 0, stream>>>(q_pw, k_pw, v_pw, out_w, ff_w1, ff_w2, wpk);

  QkvArgs qa;
  qa.dw[0] = q_dw;  qa.bng[0] = q_bng; qa.bnb[0] = q_bnb; qa.bnm[0] = q_bnm; qa.bnv[0] = q_bnv; qa.outp[0] = qt;
  qa.dw[1] = k_dw;  qa.bng[1] = k_bng; qa.bnb[1] = k_bnb; qa.bnm[1] = k_bnm; qa.bnv[1] = k_bnv; qa.outp[1] = kt;
  qa.dw[2] = v_dw;  qa.bng[2] = v_bng; qa.bnb[2] = v_bnb; qa.bnm[2] = v_bnm; qa.bnv[2] = v_bnv; qa.outp[2] = vt;
  qkv_fused_kernel<<<dim3(64, 2, 8), 256, 0, stream>>>(xnb, wpk, qa);

  softmax_kernel<<<65536, 256, 0, stream>>>(kt);
  kk_kernel<<<dim3(4, 64), 256, 0, stream>>>(qt, kt, kkp);
  kkred_kernel<<<512, 256, 0, stream>>>(kkp, kkbb);
  gateout_kernel<<<dim3(64, 64), 256, 0, stream>>>(qt, vt, kkbb, w2tb, c2, outt);
  outw_kernel<<<dim3(64, 8), 256, 0, stream>>>(outt, wpk, out_b, x, x2);

  ln_kernel<<<512, 256, 0, stream>>>(x2, ln2_g, ln2_b, xn2b);
  ff1_kernel<<<dim3(64, 4, 8), 256, 0, stream>>>(xn2b, wpk, ff_b1, hb);
  ff2_kernel<<<dim3(64, 8), 256, 0, stream>>>(hb, wpk, ff_b2, x2, out);
}